// Round 1
// baseline (637.284 us; speedup 1.0000x reference)
//
#include <hip/hip_runtime.h>

#define DEVFN __device__ __forceinline__

constexpr int BNN = 64 * 64 * 64;              // 262144 per output tensor
constexpr float SCALE = 0.08838834764831845f;  // 1/sqrt(128)
constexpr float NSLOPE = 0.01f;

// ws offsets (in floats) for transposed weights (BT[k][c] = W[c][k])
constexpr int OFF_WPRET = 0;       // [64][128]
constexpr int OFF_WQT   = 8192;    // [128][128]
constexpr int OFF_WKT   = 24576;   // [128][128]
constexpr int OFF_WSET  = 40960;   // [128][128]
constexpr int OFF_WSAPT = 57344;   // [96][128]
constexpr int OFF_WAVT  = 69632;   // [128][128]
constexpr int OFF_WF1T  = 86016;   // [128][64]
// total ws use: 94208 floats = 368 KB

template<int R>
DEVFN void zero_acc(float (&a)[R][8]) {
#pragma unroll
  for (int i = 0; i < R; ++i)
#pragma unroll
    for (int j = 0; j < 8; ++j) a[i][j] = 0.f;
}

// Register-tiled GEMM accumulate: out tile is 64 x NCOLS, NT threads,
// each thread owns RPT rows x 8 cols. A: [64][lda] (row-major, k contiguous),
// B: [K][ldb] (row-major along cols). Accumulates into acc.
template<int NCOLS, int NT, int RPT>
DEVFN void gemm_accum(int tid, const float* __restrict__ A, int lda,
                      const float* __restrict__ B, int ldb, int K,
                      float (&acc)[RPT][8]) {
  constexpr int NCG = NCOLS / 8;
  const int cg = tid % NCG, rg = tid / NCG;
  const int r0 = rg * RPT, c0 = cg * 8;
#pragma unroll 4
  for (int k = 0; k < K; ++k) {
    const float4 b0 = *reinterpret_cast<const float4*>(&B[k * ldb + c0]);
    const float4 b1 = *reinterpret_cast<const float4*>(&B[k * ldb + c0 + 4]);
#pragma unroll
    for (int i = 0; i < RPT; ++i) {
      const float a = A[(r0 + i) * lda + k];
      acc[i][0] += a * b0.x; acc[i][1] += a * b0.y;
      acc[i][2] += a * b0.z; acc[i][3] += a * b0.w;
      acc[i][4] += a * b1.x; acc[i][5] += a * b1.y;
      acc[i][6] += a * b1.z; acc[i][7] += a * b1.w;
    }
  }
}

template<int NCOLS, int NT, int RPT, bool TRANS, bool ACT, bool HASB>
DEVFN void epilogue(int tid, float (&acc)[RPT][8], float* __restrict__ O, int ldo,
                    const float* __restrict__ bias) {
  constexpr int NCG = NCOLS / 8;
  const int cg = tid % NCG, rg = tid / NCG;
  const int r0 = rg * RPT, c0 = cg * 8;
#pragma unroll
  for (int jj = 0; jj < 8; ++jj) {
    float bv = 0.f;
    if constexpr (HASB) bv = bias[c0 + jj];
#pragma unroll
    for (int i = 0; i < RPT; ++i) {
      float v = acc[i][jj] + bv;
      if constexpr (ACT) v = (v > 0.f) ? v : NSLOPE * v;
      if constexpr (TRANS) O[(c0 + jj) * ldo + (r0 + i)] = v;
      else                 O[(r0 + i) * ldo + (c0 + jj)] = v;
    }
  }
}

// Stage a 32 x NC weight k-tile from global (row-major, tight) into LDS (padded pitch)
template<int NC, int NT>
DEVFN void stageW(int tid, const float* __restrict__ src, float* __restrict__ dst) {
  constexpr int PITCH = (NC == 128) ? 132 : 68;
  constexpr int NF4 = 32 * NC / 4;
  for (int idx = tid; idx < NF4; idx += NT) {
    const int kk = idx / (NC / 4), c4 = idx % (NC / 4);
    *reinterpret_cast<float4*>(&dst[kk * PITCH + c4 * 4]) =
        *reinterpret_cast<const float4*>(&src[kk * NC + c4 * 4]);
  }
}

// Row softmax over 64x64 tile in LDS (pitch 68); also writes result to global.
DEVFN void softmax64(int tid, float* S, float scale, float* __restrict__ gout) {
  const int lane = tid & 63, wv = tid >> 6;
  for (int i = wv; i < 64; i += 4) {
    float v = S[i * 68 + lane] * scale;
    float m = v;
#pragma unroll
    for (int off = 32; off > 0; off >>= 1) m = fmaxf(m, __shfl_xor(m, off, 64));
    const float p = __expf(v - m);
    float s = p;
#pragma unroll
    for (int off = 32; off > 0; off >>= 1) s += __shfl_xor(s, off, 64);
    const float r = p / s;
    S[i * 68 + lane] = r;
    gout[i * 64 + lane] = r;
  }
}

// Transpose all weight matrices into ws: dst[k*Cout + c] = src[c*K + k]
__global__ void transpose_all(const float* __restrict__ Wpre, const float* __restrict__ Wq,
                              const float* __restrict__ Wk, const float* __restrict__ Wse,
                              const float* __restrict__ Wsap, const float* __restrict__ Wav,
                              const float* __restrict__ Wf1, float* __restrict__ ws) {
  const int m = blockIdx.y;
  const float* src; int Cout, K, off;
  switch (m) {
    case 0: src = Wpre; Cout = 128; K = 64;  off = OFF_WPRET; break;
    case 1: src = Wq;   Cout = 128; K = 128; off = OFF_WQT;   break;
    case 2: src = Wk;   Cout = 128; K = 128; off = OFF_WKT;   break;
    case 3: src = Wse;  Cout = 128; K = 128; off = OFF_WSET;  break;
    case 4: src = Wsap; Cout = 128; K = 96;  off = OFF_WSAPT; break;
    case 5: src = Wav;  Cout = 128; K = 128; off = OFF_WAVT;  break;
    default: src = Wf1; Cout = 64;  K = 128; off = OFF_WF1T;  break;
  }
  const int idx = blockIdx.x * 256 + threadIdx.x;
  if (idx < Cout * K) {
    const int c = idx / K, k = idx - c * K;
    ws[off + k * Cout + c] = src[idx];
  }
}

// Fused per-batch attention stages 1+2. Grid: 64 blocks (one per batch), 256 threads.
__global__ __launch_bounds__(256) void stage12(const float* __restrict__ states,
                                               const float* __restrict__ b_se_pre,
                                               const float* __restrict__ b_se,
                                               const float* __restrict__ ws,
                                               float* __restrict__ out) {
  __shared__ float sA[64 * 68];  // states -> scores -> w
  __shared__ float sE[8704];     // e [64][132] -> q2 [64][132]
  __shared__ float sQ[8704];     // q1 [64][132] -> av_pre [64][132] -> k2T [128][68]
  __shared__ float sK[8704];     // k1T [128][68] -> se [64][132]
  const int b = blockIdx.x, tid = threadIdx.x;

  for (int idx = tid; idx < 4096; idx += 256) {
    const int i = idx >> 6, c = idx & 63;
    sA[i * 68 + c] = states[(b * 64 + i) * 64 + c];
  }
  __syncthreads();
  { // e = lrelu(states @ WpreT + b_se_pre) -> sE
    float acc[4][8]; zero_acc(acc);
    gemm_accum<128, 256, 4>(tid, sA, 68, ws + OFF_WPRET, 128, 64, acc);
    epilogue<128, 256, 4, false, true, true>(tid, acc, sE, 132, b_se_pre);
  }
  __syncthreads();
  { // q1 = e @ WqT -> sQ
    float acc[4][8]; zero_acc(acc);
    gemm_accum<128, 256, 4>(tid, sE, 132, ws + OFF_WQT, 128, 128, acc);
    epilogue<128, 256, 4, false, false, false>(tid, acc, sQ, 132, nullptr);
  }
  { // k1 = e @ WkT -> sK transposed [128][68]
    float acc[4][8]; zero_acc(acc);
    gemm_accum<128, 256, 4>(tid, sE, 132, ws + OFF_WKT, 128, 128, acc);
    epilogue<128, 256, 4, true, false, false>(tid, acc, sK, 68, nullptr);
  }
  __syncthreads();
  { // s1 = q1 @ k1^T -> sA
    float acc[2][8]; zero_acc(acc);
    gemm_accum<64, 256, 2>(tid, sQ, 132, sK, 68, 128, acc);
    epilogue<64, 256, 2, false, false, false>(tid, acc, sA, 68, nullptr);
  }
  __syncthreads();
  softmax64(tid, sA, SCALE, out + BNN + b * 4096);  // w_pre
  __syncthreads();
  { // av_pre = w_pre @ e -> sQ
    float acc[4][8]; zero_acc(acc);
    gemm_accum<128, 256, 4>(tid, sA, 68, sE, 132, 64, acc);
    epilogue<128, 256, 4, false, false, false>(tid, acc, sQ, 132, nullptr);
  }
  __syncthreads();
  { // se = lrelu(av_pre @ WseT + b_se) -> sK
    float acc[4][8]; zero_acc(acc);
    gemm_accum<128, 256, 4>(tid, sQ, 132, ws + OFF_WSET, 128, 128, acc);
    epilogue<128, 256, 4, false, true, true>(tid, acc, sK, 132, b_se);
  }
  __syncthreads();
  { // q2 = se @ WqT -> sE
    float acc[4][8]; zero_acc(acc);
    gemm_accum<128, 256, 4>(tid, sK, 132, ws + OFF_WQT, 128, 128, acc);
    epilogue<128, 256, 4, false, false, false>(tid, acc, sE, 132, nullptr);
  }
  { // k2 = se @ WkT -> sQ transposed [128][68]
    float acc[4][8]; zero_acc(acc);
    gemm_accum<128, 256, 4>(tid, sK, 132, ws + OFF_WKT, 128, 128, acc);
    epilogue<128, 256, 4, true, false, false>(tid, acc, sQ, 68, nullptr);
  }
  __syncthreads();
  { // s2 = q2 @ k2^T -> sA
    float acc[2][8]; zero_acc(acc);
    gemm_accum<64, 256, 2>(tid, sE, 132, sQ, 68, 128, acc);
    epilogue<64, 256, 2, false, false, false>(tid, acc, sA, 68, nullptr);
  }
  __syncthreads();
  softmax64(tid, sA, SCALE, out + 2 * BNN + b * 4096);  // w
}

// Fused stage 3: one block per (b, j). Grid 4096, 512 threads.
__global__ __launch_bounds__(512) void bigfuse(const float* __restrict__ states,
                                               const float* __restrict__ policies,
                                               const float* __restrict__ actions,
                                               const float* __restrict__ b_sap,
                                               const float* __restrict__ Wf2,
                                               const float* __restrict__ ws,
                                               float* __restrict__ out) {
  __shared__ float Xs[64 * 100];  // oap rows [64][96] (pitch 100); later h [64][68]
  __shared__ float Wt[32 * 132];  // weight k-tile
  __shared__ float Es[64 * 132];  // emb, then node
  __shared__ float Vs[64 * 132];  // av
  __shared__ float wS[64 * 68];   // w[b]
  const int tid = threadIdx.x;
  const int bj = blockIdx.x, b = bj >> 6, j = bj & 63;

  for (int idx = tid; idx < 64 * 96; idx += 512) {
    const int r = idx / 96, c = idx - r * 96;
    float v;
    if (c < 64) v = states[(b * 64 + r) * 64 + c];
    else {
      const int a = c - 64;
      v = (r == j) ? policies[(b * 64 + r) * 32 + a] : actions[(b * 64 + r) * 32 + a];
    }
    Xs[r * 100 + c] = v;
  }
  const float* wg = out + 2 * BNN + b * 4096;  // w written by stage12
  for (int idx = tid; idx < 4096; idx += 512) {
    wS[(idx >> 6) * 68 + (idx & 63)] = wg[idx];
  }
  __syncthreads();

  float acc[2][8];
  // emb = lrelu(X @ WsapT + b_sap) -> Es
  zero_acc(acc);
  for (int kt = 0; kt < 3; ++kt) {
    stageW<128, 512>(tid, ws + OFF_WSAPT + kt * 32 * 128, Wt);
    __syncthreads();
    gemm_accum<128, 512, 2>(tid, Xs + kt * 32, 100, Wt, 132, 32, acc);
    __syncthreads();
  }
  epilogue<128, 512, 2, false, true, true>(tid, acc, Es, 132, b_sap);
  // av = emb @ WavT -> Vs
  zero_acc(acc);
  for (int kt = 0; kt < 4; ++kt) {
    stageW<128, 512>(tid, ws + OFF_WAVT + kt * 32 * 128, Wt);
    __syncthreads();
    gemm_accum<128, 512, 2>(tid, Es + kt * 32, 132, Wt, 132, 32, acc);
    __syncthreads();
  }
  epilogue<128, 512, 2, false, false, false>(tid, acc, Vs, 132, nullptr);
  __syncthreads();
  // node = w @ av -> Es
  zero_acc(acc);
  gemm_accum<128, 512, 2>(tid, wS, 68, Vs, 132, 64, acc);
  epilogue<128, 512, 2, false, false, false>(tid, acc, Es, 132, nullptr);
  // h = lrelu(node @ Wf1T) -> Xs (reused, pitch 68)
  float acch[1][8];
  zero_acc(acch);
  for (int kt = 0; kt < 4; ++kt) {
    stageW<64, 512>(tid, ws + OFF_WF1T + kt * 32 * 64, Wt);
    __syncthreads();
    gemm_accum<64, 512, 1>(tid, Es + kt * 32, 132, Wt, 68, 32, acch);
    __syncthreads();
  }
  epilogue<64, 512, 1, false, true, false>(tid, acch, Xs, 68, nullptr);
  __syncthreads();
  // value[b][i][j] = h[i][:] . Wf2
  {
    const int i = tid >> 3, part = tid & 7;
    float v = 0.f;
#pragma unroll
    for (int ff = 0; ff < 8; ++ff) {
      const int f = part * 8 + ff;
      v += Xs[i * 68 + f] * Wf2[f];
    }
    v += __shfl_xor(v, 1, 64);
    v += __shfl_xor(v, 2, 64);
    v += __shfl_xor(v, 4, 64);
    if (part == 0) out[(b * 64 + i) * 64 + j] = v;
  }
}

extern "C" void kernel_launch(void* const* d_in, const int* in_sizes, int n_in,
                              void* d_out, int out_size, void* d_ws, size_t ws_size,
                              hipStream_t stream) {
  const float* states   = (const float*)d_in[0];
  const float* policies = (const float*)d_in[1];
  const float* actions  = (const float*)d_in[2];
  const float* W_se_pre = (const float*)d_in[3];
  const float* b_se_pre = (const float*)d_in[4];
  const float* W_key    = (const float*)d_in[5];
  const float* W_query  = (const float*)d_in[6];
  const float* W_se     = (const float*)d_in[7];
  const float* b_se     = (const float*)d_in[8];
  const float* W_sap    = (const float*)d_in[9];
  const float* b_sap    = (const float*)d_in[10];
  const float* W_av     = (const float*)d_in[11];
  const float* W_f1     = (const float*)d_in[12];
  const float* W_f2     = (const float*)d_in[13];
  float* out = (float*)d_out;
  float* ws  = (float*)d_ws;

  hipLaunchKernelGGL(transpose_all, dim3(64, 7), dim3(256), 0, stream,
                     W_se_pre, W_query, W_key, W_se, W_sap, W_av, W_f1, ws);
  hipLaunchKernelGGL(stage12, dim3(64), dim3(256), 0, stream,
                     states, b_se_pre, b_se, ws, out);
  hipLaunchKernelGGL(bigfuse, dim3(4096), dim3(512), 0, stream,
                     states, policies, actions, b_sap, W_f2, ws, out);
}

// Round 2
// 191.957 us; speedup vs baseline: 3.3199x; 3.3199x over previous
//
#include <hip/hip_runtime.h>

#define DEVFN __device__ __forceinline__

constexpr int BNN = 64 * 64 * 64;              // 262144 per output tensor
constexpr float SCALE = 0.08838834764831845f;  // 1/sqrt(128)
constexpr float NSLOPE = 0.01f;

// ws offsets (in floats) for transposed weights (BT[k][c] = W[c][k])
constexpr int OFF_WPRET = 0;       // [64][128]
constexpr int OFF_WQT   = 8192;    // [128][128]
constexpr int OFF_WKT   = 24576;   // [128][128]
constexpr int OFF_WSET  = 40960;   // [128][128]
constexpr int OFF_WSAPT = 57344;   // [96][128]
constexpr int OFF_WAVT  = 69632;   // [128][128]
constexpr int OFF_WF1T  = 86016;   // [128][64]
constexpr int OFF_AVACT = 98304;   // [B][64][128] = 524288 floats
constexpr int OFF_HD    = 98304 + 524288;  // [B][64][64] = 262144 floats
// total ws use: 884736 floats = 3.54 MB

template<int R>
DEVFN void zero_acc(float (&a)[R][8]) {
#pragma unroll
  for (int i = 0; i < R; ++i)
#pragma unroll
    for (int j = 0; j < 8; ++j) a[i][j] = 0.f;
}

// Register-tiled GEMM accumulate: out tile is ROWS x NCOLS where
// ROWS = (NT/(NCOLS/8))*RPT. Each thread owns RPT rows x 8 cols.
// A: [ROWS][lda] (k contiguous), B: [K][ldb]. Accumulates into acc.
template<int NCOLS, int NT, int RPT>
DEVFN void gemm_accum(int tid, const float* __restrict__ A, int lda,
                      const float* __restrict__ B, int ldb, int K,
                      float (&acc)[RPT][8]) {
  constexpr int NCG = NCOLS / 8;
  const int cg = tid % NCG, rg = tid / NCG;
  const int r0 = rg * RPT, c0 = cg * 8;
#pragma unroll 4
  for (int k = 0; k < K; ++k) {
    const float4 b0 = *reinterpret_cast<const float4*>(&B[k * ldb + c0]);
    const float4 b1 = *reinterpret_cast<const float4*>(&B[k * ldb + c0 + 4]);
#pragma unroll
    for (int i = 0; i < RPT; ++i) {
      const float a = A[(r0 + i) * lda + k];
      acc[i][0] += a * b0.x; acc[i][1] += a * b0.y;
      acc[i][2] += a * b0.z; acc[i][3] += a * b0.w;
      acc[i][4] += a * b1.x; acc[i][5] += a * b1.y;
      acc[i][6] += a * b1.z; acc[i][7] += a * b1.w;
    }
  }
}

template<int NCOLS, int NT, int RPT, bool TRANS, bool ACT, bool HASB>
DEVFN void epilogue(int tid, float (&acc)[RPT][8], float* __restrict__ O, int ldo,
                    const float* __restrict__ bias) {
  constexpr int NCG = NCOLS / 8;
  const int cg = tid % NCG, rg = tid / NCG;
  const int r0 = rg * RPT, c0 = cg * 8;
#pragma unroll
  for (int jj = 0; jj < 8; ++jj) {
    float bv = 0.f;
    if constexpr (HASB) bv = bias[c0 + jj];
#pragma unroll
    for (int i = 0; i < RPT; ++i) {
      float v = acc[i][jj] + bv;
      if constexpr (ACT) v = (v > 0.f) ? v : NSLOPE * v;
      if constexpr (TRANS) O[(c0 + jj) * ldo + (r0 + i)] = v;
      else                 O[(r0 + i) * ldo + (c0 + jj)] = v;
    }
  }
}

// Row softmax over 64x64 tile in LDS (pitch 68); also writes result to global.
template<int NT>
DEVFN void softmax64(int tid, float* S, float scale, float* __restrict__ gout) {
  const int lane = tid & 63, wv = tid >> 6;
  for (int i = wv; i < 64; i += NT / 64) {
    float v = S[i * 68 + lane] * scale;
    float m = v;
#pragma unroll
    for (int off = 32; off > 0; off >>= 1) m = fmaxf(m, __shfl_xor(m, off, 64));
    const float p = __expf(v - m);
    float s = p;
#pragma unroll
    for (int off = 32; off > 0; off >>= 1) s += __shfl_xor(s, off, 64);
    const float r = p / s;
    S[i * 68 + lane] = r;
    gout[i * 64 + lane] = r;
  }
}

// Transpose all weight matrices into ws: dst[k*Cout + c] = src[c*K + k]
__global__ void transpose_all(const float* __restrict__ Wpre, const float* __restrict__ Wq,
                              const float* __restrict__ Wk, const float* __restrict__ Wse,
                              const float* __restrict__ Wsap, const float* __restrict__ Wav,
                              const float* __restrict__ Wf1, float* __restrict__ ws) {
  const int m = blockIdx.y;
  const float* src; int Cout, K, off;
  switch (m) {
    case 0: src = Wpre; Cout = 128; K = 64;  off = OFF_WPRET; break;
    case 1: src = Wq;   Cout = 128; K = 128; off = OFF_WQT;   break;
    case 2: src = Wk;   Cout = 128; K = 128; off = OFF_WKT;   break;
    case 3: src = Wse;  Cout = 128; K = 128; off = OFF_WSET;  break;
    case 4: src = Wsap; Cout = 128; K = 96;  off = OFF_WSAPT; break;
    case 5: src = Wav;  Cout = 128; K = 128; off = OFF_WAVT;  break;
    default: src = Wf1; Cout = 64;  K = 128; off = OFF_WF1T;  break;
  }
  const int idx = blockIdx.x * 256 + threadIdx.x;
  if (idx < Cout * K) {
    const int c = idx / K, k = idx - c * K;
    ws[off + k * Cout + c] = src[idx];
  }
}

// prep: per-(b, quarter) rows: E_act/E_pol -> av_act (to ws), delta -> hd (to ws).
// Grid 256 blocks x 256 threads, 16 rows per block.
__global__ __launch_bounds__(256) void prep(const float* __restrict__ states,
                                            const float* __restrict__ policies,
                                            const float* __restrict__ actions,
                                            const float* __restrict__ b_sap,
                                            float* __restrict__ ws) {
  __shared__ float Xa[16 * 100];
  __shared__ float Xp[16 * 100];
  __shared__ float Ea[16 * 132];
  __shared__ float Ep[16 * 132];
  __shared__ float Dd[16 * 132];
  const int tid = threadIdx.x;
  const int b = blockIdx.x >> 2, rq = blockIdx.x & 3;
  const int r0g = b * 64 + rq * 16;  // first global row (b*64+k)

  for (int idx = tid; idx < 1024; idx += 256) {
    const int r = idx >> 6, c = idx & 63;
    const float s = states[(r0g + r) * 64 + c];
    Xa[r * 100 + c] = s;
    Xp[r * 100 + c] = s;
  }
  for (int idx = tid; idx < 512; idx += 256) {
    const int r = idx >> 5, c = idx & 31;
    Xa[r * 100 + 64 + c] = actions[(r0g + r) * 32 + c];
    Xp[r * 100 + 64 + c] = policies[(r0g + r) * 32 + c];
  }
  __syncthreads();
  { // E_act = lrelu(Xa @ WsapT + b_sap)
    float acc[1][8]; zero_acc(acc);
    gemm_accum<128, 256, 1>(tid, Xa, 100, ws + OFF_WSAPT, 128, 96, acc);
    epilogue<128, 256, 1, false, true, true>(tid, acc, Ea, 132, b_sap);
  }
  { // E_pol
    float acc[1][8]; zero_acc(acc);
    gemm_accum<128, 256, 1>(tid, Xp, 100, ws + OFF_WSAPT, 128, 96, acc);
    epilogue<128, 256, 1, false, true, true>(tid, acc, Ep, 132, b_sap);
  }
  __syncthreads();
  // Ep -= Ea (E-diff)
  for (int idx = tid; idx < 2048; idx += 256) {
    const int r = idx >> 7, c = idx & 127;
    Ep[r * 132 + c] -= Ea[r * 132 + c];
  }
  __syncthreads();
  { // av_act = Ea @ WavT -> ws (global, tight [64][128] per b)
    float acc[1][8]; zero_acc(acc);
    gemm_accum<128, 256, 1>(tid, Ea, 132, ws + OFF_WAVT, 128, 128, acc);
    epilogue<128, 256, 1, false, false, false>(tid, acc, ws + OFF_AVACT + r0g * 128, 128, nullptr);
  }
  { // delta = Ediff @ WavT -> Dd
    float acc[1][8]; zero_acc(acc);
    gemm_accum<128, 256, 1>(tid, Ep, 132, ws + OFF_WAVT, 128, 128, acc);
    epilogue<128, 256, 1, false, false, false>(tid, acc, Dd, 132, nullptr);
  }
  __syncthreads();
  // hd = delta @ Wf1T -> ws (tight [64][64] per b)
  if (tid < 128) {
    float acc[1][8]; zero_acc(acc);
    gemm_accum<64, 128, 1>(tid, Dd, 132, ws + OFF_WF1T, 64, 128, acc);
    epilogue<64, 128, 1, false, false, false>(tid, acc, ws + OFF_HD + r0g * 64, 64, nullptr);
  }
}

// Fused per-batch attention stages 1+2. Grid: 64 blocks, 512 threads.
__global__ __launch_bounds__(512) void stage12(const float* __restrict__ states,
                                               const float* __restrict__ b_se_pre,
                                               const float* __restrict__ b_se,
                                               const float* __restrict__ ws,
                                               float* __restrict__ out) {
  __shared__ float sA[64 * 68];  // states -> scores -> w
  __shared__ float sE[8704];     // e [64][132] -> q2 [64][132]
  __shared__ float sQ[8704];     // q1 [64][132] -> av_pre [64][132] -> k2T [128][68]
  __shared__ float sK[8704];     // k1T [128][68] -> se [64][132]
  const int b = blockIdx.x, tid = threadIdx.x;

  for (int idx = tid; idx < 4096; idx += 512) {
    const int i = idx >> 6, c = idx & 63;
    sA[i * 68 + c] = states[(b * 64 + i) * 64 + c];
  }
  __syncthreads();
  { // e = lrelu(states @ WpreT + b_se_pre) -> sE
    float acc[2][8]; zero_acc(acc);
    gemm_accum<128, 512, 2>(tid, sA, 68, ws + OFF_WPRET, 128, 64, acc);
    epilogue<128, 512, 2, false, true, true>(tid, acc, sE, 132, b_se_pre);
  }
  __syncthreads();
  { // q1 = e @ WqT -> sQ
    float acc[2][8]; zero_acc(acc);
    gemm_accum<128, 512, 2>(tid, sE, 132, ws + OFF_WQT, 128, 128, acc);
    epilogue<128, 512, 2, false, false, false>(tid, acc, sQ, 132, nullptr);
  }
  { // k1 = e @ WkT -> sK transposed [128][68]
    float acc[2][8]; zero_acc(acc);
    gemm_accum<128, 512, 2>(tid, sE, 132, ws + OFF_WKT, 128, 128, acc);
    epilogue<128, 512, 2, true, false, false>(tid, acc, sK, 68, nullptr);
  }
  __syncthreads();
  { // s1 = q1 @ k1^T -> sA
    float acc[1][8]; zero_acc(acc);
    gemm_accum<64, 512, 1>(tid, sQ, 132, sK, 68, 128, acc);
    epilogue<64, 512, 1, false, false, false>(tid, acc, sA, 68, nullptr);
  }
  __syncthreads();
  softmax64<512>(tid, sA, SCALE, out + BNN + b * 4096);  // w_pre
  __syncthreads();
  { // av_pre = w_pre @ e -> sQ
    float acc[2][8]; zero_acc(acc);
    gemm_accum<128, 512, 2>(tid, sA, 68, sE, 132, 64, acc);
    epilogue<128, 512, 2, false, false, false>(tid, acc, sQ, 132, nullptr);
  }
  __syncthreads();
  { // se = lrelu(av_pre @ WseT + b_se) -> sK
    float acc[2][8]; zero_acc(acc);
    gemm_accum<128, 512, 2>(tid, sQ, 132, ws + OFF_WSET, 128, 128, acc);
    epilogue<128, 512, 2, false, true, true>(tid, acc, sK, 132, b_se);
  }
  __syncthreads();
  { // q2 = se @ WqT -> sE
    float acc[2][8]; zero_acc(acc);
    gemm_accum<128, 512, 2>(tid, sK, 132, ws + OFF_WQT, 128, 128, acc);
    epilogue<128, 512, 2, false, false, false>(tid, acc, sE, 132, nullptr);
  }
  { // k2 = se @ WkT -> sQ transposed [128][68]
    float acc[2][8]; zero_acc(acc);
    gemm_accum<128, 512, 2>(tid, sK, 132, ws + OFF_WKT, 128, 128, acc);
    epilogue<128, 512, 2, true, false, false>(tid, acc, sQ, 68, nullptr);
  }
  __syncthreads();
  { // s2 = q2 @ k2^T -> sA
    float acc[1][8]; zero_acc(acc);
    gemm_accum<64, 512, 1>(tid, sE, 132, sQ, 68, 128, acc);
    epilogue<64, 512, 1, false, false, false>(tid, acc, sA, 68, nullptr);
  }
  __syncthreads();
  softmax64<512>(tid, sA, SCALE, out + 2 * BNN + b * 4096);  // w
}

// finale: per batch. node_base = w @ av_act, h_base = node_base @ Wf1T,
// value[b,i,j] = sum_f lrelu(h_base[i,f] + w[i,j]*hd[j,f]) * Wf2[f].
__global__ __launch_bounds__(512) void finale(const float* __restrict__ Wf2g,
                                              const float* __restrict__ ws,
                                              float* __restrict__ out) {
  __shared__ float wS[64 * 68];
  __shared__ float NB[64 * 132];
  __shared__ float Hb[64 * 68];
  __shared__ float Hd[64 * 69];  // pitch 69: head reads Hd[j*69+f] across lanes -> 2-way max
  __shared__ float Wf2s[64];
  const int b = blockIdx.x, tid = threadIdx.x;

  const float* wg = out + 2 * BNN + b * 4096;
  for (int idx = tid; idx < 4096; idx += 512)
    wS[(idx >> 6) * 68 + (idx & 63)] = wg[idx];
  for (int idx = tid; idx < 4096; idx += 512)
    Hd[(idx >> 6) * 69 + (idx & 63)] = ws[OFF_HD + b * 4096 + idx];
  if (tid < 64) Wf2s[tid] = Wf2g[tid];
  __syncthreads();
  { // node_base = w @ av_act (av_act read from global ws)
    float acc[2][8]; zero_acc(acc);
    gemm_accum<128, 512, 2>(tid, wS, 68, ws + OFF_AVACT + b * 8192, 128, 64, acc);
    epilogue<128, 512, 2, false, false, false>(tid, acc, NB, 132, nullptr);
  }
  __syncthreads();
  { // h_base = node_base @ Wf1T (no activation!)
    float acc[1][8]; zero_acc(acc);
    gemm_accum<64, 512, 1>(tid, NB, 132, ws + OFF_WF1T, 64, 128, acc);
    epilogue<64, 512, 1, false, false, false>(tid, acc, Hb, 68, nullptr);
  }
  __syncthreads();
  // head: thread -> (j = tid&63, i = iw*8+ii for ii<8)
  const int j = tid & 63, iw = tid >> 6;
  float wv[8], acc8[8];
#pragma unroll
  for (int ii = 0; ii < 8; ++ii) {
    wv[ii] = wS[(iw * 8 + ii) * 68 + j];
    acc8[ii] = 0.f;
  }
  for (int f = 0; f < 64; ++f) {
    const float hdv = Hd[j * 69 + f];
    const float wf = Wf2s[f];
#pragma unroll
    for (int ii = 0; ii < 8; ++ii) {
      float t = Hb[(iw * 8 + ii) * 68 + f] + wv[ii] * hdv;  // Hb read is wave-uniform (broadcast)
      t = (t > 0.f) ? t : NSLOPE * t;
      acc8[ii] += t * wf;
    }
  }
#pragma unroll
  for (int ii = 0; ii < 8; ++ii)
    out[(b * 64 + iw * 8 + ii) * 64 + j] = acc8[ii];
}

extern "C" void kernel_launch(void* const* d_in, const int* in_sizes, int n_in,
                              void* d_out, int out_size, void* d_ws, size_t ws_size,
                              hipStream_t stream) {
  const float* states   = (const float*)d_in[0];
  const float* policies = (const float*)d_in[1];
  const float* actions  = (const float*)d_in[2];
  const float* W_se_pre = (const float*)d_in[3];
  const float* b_se_pre = (const float*)d_in[4];
  const float* W_key    = (const float*)d_in[5];
  const float* W_query  = (const float*)d_in[6];
  const float* W_se     = (const float*)d_in[7];
  const float* b_se     = (const float*)d_in[8];
  const float* W_sap    = (const float*)d_in[9];
  const float* b_sap    = (const float*)d_in[10];
  const float* W_av     = (const float*)d_in[11];
  const float* W_f1     = (const float*)d_in[12];
  const float* W_f2     = (const float*)d_in[13];
  float* out = (float*)d_out;
  float* ws  = (float*)d_ws;

  hipLaunchKernelGGL(transpose_all, dim3(64, 7), dim3(256), 0, stream,
                     W_se_pre, W_query, W_key, W_se, W_sap, W_av, W_f1, ws);
  hipLaunchKernelGGL(prep, dim3(256), dim3(256), 0, stream,
                     states, policies, actions, b_sap, ws);
  hipLaunchKernelGGL(stage12, dim3(64), dim3(512), 0, stream,
                     states, b_se_pre, b_se, ws, out);
  hipLaunchKernelGGL(finale, dim3(64), dim3(512), 0, stream,
                     W_f2, ws, out);
}

// Round 3
// 134.242 us; speedup vs baseline: 4.7473x; 1.4299x over previous
//
#include <hip/hip_runtime.h>

#define DEVFN __device__ __forceinline__

constexpr int BNN = 64 * 64 * 64;              // 262144 per output tensor
constexpr float SCALE = 0.08838834764831845f;  // 1/sqrt(128)
constexpr float NSLOPE = 0.01f;

// ---- ws layout (floats) ----
// weights transposed (BT[k][c] = W[c][k])
constexpr int OFF_WPRET = 0;       // [64][128]
constexpr int OFF_WQT   = 8192;    // [128][128]
constexpr int OFF_WKT   = 24576;   // [128][128]
constexpr int OFF_WSET  = 40960;   // [128][128]
constexpr int OFF_WSAPT = 57344;   // [96][128]
constexpr int OFF_WAVT  = 69632;   // [128][128]
constexpr int OFF_WF1T  = 86016;   // [128][64]
// wide-pipeline intermediates
constexpr int OFF_E     = 98304;             // [4096][128]
constexpr int OFF_Q     = 98304 + 524288;    // [4096][128]
constexpr int OFF_K     = 98304 + 1048576;   // [B][128][64] (feature-major); later HB [4096][64]
constexpr int OFF_AVACT = 98304 + 1572864;   // [B][64][128]
constexpr int OFF_HD    = 98304 + 2097152;   // [B][64][64]
constexpr size_t NEED_BYTES = (size_t)(OFF_HD + 262144) * 4;  // 9.83 MB
// fallback layout (round-2, 3.54 MB proven)
constexpr int OFF_AVACT_F = 98304;
constexpr int OFF_HD_F    = 622592;

// ===================== small-row GEMM helpers (256 thr, 16 rows) =====================

template<int NCOLS, int NT>
DEVFN void g16(int tid, const float* __restrict__ A, int lda,
               const float* __restrict__ B, int ldb, int K, float (&acc)[8]) {
  constexpr int NCG = NCOLS / 8;
  const int cg = tid % NCG, rg = tid / NCG;
  const int c0 = cg * 8;
#pragma unroll 4
  for (int k = 0; k < K; ++k) {
    const float4 b0 = *reinterpret_cast<const float4*>(&B[k * ldb + c0]);
    const float4 b1 = *reinterpret_cast<const float4*>(&B[k * ldb + c0 + 4]);
    const float a = A[rg * lda + k];
    acc[0] += a * b0.x; acc[1] += a * b0.y; acc[2] += a * b0.z; acc[3] += a * b0.w;
    acc[4] += a * b1.x; acc[5] += a * b1.y; acc[6] += a * b1.z; acc[7] += a * b1.w;
  }
}

template<int NCOLS, int NT>
DEVFN void g16_dualB(int tid, const float* __restrict__ A, int lda,
                     const float* __restrict__ B0, const float* __restrict__ B1,
                     int ldb, int K, float (&a0)[8], float (&a1)[8]) {
  constexpr int NCG = NCOLS / 8;
  const int cg = tid % NCG, rg = tid / NCG;
  const int c0 = cg * 8;
#pragma unroll 4
  for (int k = 0; k < K; ++k) {
    const float4 p0 = *reinterpret_cast<const float4*>(&B0[k * ldb + c0]);
    const float4 p1 = *reinterpret_cast<const float4*>(&B0[k * ldb + c0 + 4]);
    const float4 q0 = *reinterpret_cast<const float4*>(&B1[k * ldb + c0]);
    const float4 q1 = *reinterpret_cast<const float4*>(&B1[k * ldb + c0 + 4]);
    const float a = A[rg * lda + k];
    a0[0] += a * p0.x; a0[1] += a * p0.y; a0[2] += a * p0.z; a0[3] += a * p0.w;
    a0[4] += a * p1.x; a0[5] += a * p1.y; a0[6] += a * p1.z; a0[7] += a * p1.w;
    a1[0] += a * q0.x; a1[1] += a * q0.y; a1[2] += a * q0.z; a1[3] += a * q0.w;
    a1[4] += a * q1.x; a1[5] += a * q1.y; a1[6] += a * q1.z; a1[7] += a * q1.w;
  }
}

template<int NCOLS, int NT>
DEVFN void g16_dualA(int tid, const float* __restrict__ A0, const float* __restrict__ A1,
                     int lda, const float* __restrict__ B, int ldb, int K,
                     float (&a0)[8], float (&a1)[8]) {
  constexpr int NCG = NCOLS / 8;
  const int cg = tid % NCG, rg = tid / NCG;
  const int c0 = cg * 8;
#pragma unroll 4
  for (int k = 0; k < K; ++k) {
    const float4 b0 = *reinterpret_cast<const float4*>(&B[k * ldb + c0]);
    const float4 b1 = *reinterpret_cast<const float4*>(&B[k * ldb + c0 + 4]);
    const float x = A0[rg * lda + k];
    const float y = A1[rg * lda + k];
    a0[0] += x * b0.x; a0[1] += x * b0.y; a0[2] += x * b0.z; a0[3] += x * b0.w;
    a0[4] += x * b1.x; a0[5] += x * b1.y; a0[6] += x * b1.z; a0[7] += x * b1.w;
    a1[0] += y * b0.x; a1[1] += y * b0.y; a1[2] += y * b0.z; a1[3] += y * b0.w;
    a1[4] += y * b1.x; a1[5] += y * b1.y; a1[6] += y * b1.z; a1[7] += y * b1.w;
  }
}

template<int NCOLS, bool TRANS, bool ACT, bool HASB>
DEVFN void e16(int tid, float (&acc)[8], float* __restrict__ O, int ldo,
               const float* __restrict__ bias) {
  constexpr int NCG = NCOLS / 8;
  const int cg = tid % NCG, rg = tid / NCG;
  const int c0 = cg * 8;
#pragma unroll
  for (int jj = 0; jj < 8; ++jj) {
    float v = acc[jj];
    if constexpr (HASB) v += bias[c0 + jj];
    if constexpr (ACT) v = (v > 0.f) ? v : NSLOPE * v;
    if constexpr (TRANS) O[(c0 + jj) * ldo + rg] = v;
    else                 O[rg * ldo + (c0 + jj)] = v;
  }
}

// Stage a 32 x NC weight k-tile from global (row-major, tight) into LDS (padded pitch)
template<int NC, int NT>
DEVFN void stageW(int tid, const float* __restrict__ src, float* __restrict__ dst) {
  constexpr int PITCH = (NC == 128) ? 132 : 68;
  constexpr int NF4 = 32 * NC / 4;
  for (int idx = tid; idx < NF4; idx += NT) {
    const int kk = idx / (NC / 4), c4 = idx % (NC / 4);
    *reinterpret_cast<float4*>(&dst[kk * PITCH + c4 * 4]) =
        *reinterpret_cast<const float4*>(&src[kk * NC + c4 * 4]);
  }
}

// ===================== legacy helpers (fallback path) =====================

template<int R>
DEVFN void zero_acc(float (&a)[R][8]) {
#pragma unroll
  for (int i = 0; i < R; ++i)
#pragma unroll
    for (int j = 0; j < 8; ++j) a[i][j] = 0.f;
}

template<int NCOLS, int NT, int RPT>
DEVFN void gemm_accum(int tid, const float* __restrict__ A, int lda,
                      const float* __restrict__ B, int ldb, int K,
                      float (&acc)[RPT][8]) {
  constexpr int NCG = NCOLS / 8;
  const int cg = tid % NCG, rg = tid / NCG;
  const int r0 = rg * RPT, c0 = cg * 8;
#pragma unroll 4
  for (int k = 0; k < K; ++k) {
    const float4 b0 = *reinterpret_cast<const float4*>(&B[k * ldb + c0]);
    const float4 b1 = *reinterpret_cast<const float4*>(&B[k * ldb + c0 + 4]);
#pragma unroll
    for (int i = 0; i < RPT; ++i) {
      const float a = A[(r0 + i) * lda + k];
      acc[i][0] += a * b0.x; acc[i][1] += a * b0.y;
      acc[i][2] += a * b0.z; acc[i][3] += a * b0.w;
      acc[i][4] += a * b1.x; acc[i][5] += a * b1.y;
      acc[i][6] += a * b1.z; acc[i][7] += a * b1.w;
    }
  }
}

template<int NCOLS, int NT, int RPT, bool TRANS, bool ACT, bool HASB>
DEVFN void epilogue(int tid, float (&acc)[RPT][8], float* __restrict__ O, int ldo,
                    const float* __restrict__ bias) {
  constexpr int NCG = NCOLS / 8;
  const int cg = tid % NCG, rg = tid / NCG;
  const int r0 = rg * RPT, c0 = cg * 8;
#pragma unroll
  for (int jj = 0; jj < 8; ++jj) {
    float bv = 0.f;
    if constexpr (HASB) bv = bias[c0 + jj];
#pragma unroll
    for (int i = 0; i < RPT; ++i) {
      float v = acc[i][jj] + bv;
      if constexpr (ACT) v = (v > 0.f) ? v : NSLOPE * v;
      if constexpr (TRANS) O[(c0 + jj) * ldo + (r0 + i)] = v;
      else                 O[(r0 + i) * ldo + (c0 + jj)] = v;
    }
  }
}

template<int NT>
DEVFN void softmax64(int tid, float* S, float scale, float* __restrict__ gout) {
  const int lane = tid & 63, wv = tid >> 6;
  for (int i = wv; i < 64; i += NT / 64) {
    float v = S[i * 68 + lane] * scale;
    float m = v;
#pragma unroll
    for (int off = 32; off > 0; off >>= 1) m = fmaxf(m, __shfl_xor(m, off, 64));
    const float p = __expf(v - m);
    float s = p;
#pragma unroll
    for (int off = 32; off > 0; off >>= 1) s += __shfl_xor(s, off, 64);
    const float r = p / s;
    S[i * 68 + lane] = r;
    gout[i * 64 + lane] = r;
  }
}

// ===================== kernels =====================

__global__ void transpose_all(const float* __restrict__ Wpre, const float* __restrict__ Wq,
                              const float* __restrict__ Wk, const float* __restrict__ Wse,
                              const float* __restrict__ Wsap, const float* __restrict__ Wav,
                              const float* __restrict__ Wf1, float* __restrict__ ws) {
  const int m = blockIdx.y;
  const float* src; int Cout, K, off;
  switch (m) {
    case 0: src = Wpre; Cout = 128; K = 64;  off = OFF_WPRET; break;
    case 1: src = Wq;   Cout = 128; K = 128; off = OFF_WQT;   break;
    case 2: src = Wk;   Cout = 128; K = 128; off = OFF_WKT;   break;
    case 3: src = Wse;  Cout = 128; K = 128; off = OFF_WSET;  break;
    case 4: src = Wsap; Cout = 128; K = 96;  off = OFF_WSAPT; break;
    case 5: src = Wav;  Cout = 128; K = 128; off = OFF_WAVT;  break;
    default: src = Wf1; Cout = 64;  K = 128; off = OFF_WF1T;  break;
  }
  const int idx = blockIdx.x * 256 + threadIdx.x;
  if (idx < Cout * K) {
    const int c = idx / K, k = idx - c * K;
    ws[off + k * Cout + c] = src[idx];
  }
}

// prep: 16 rows/block: E_act/E_pol (dual-A) -> av_act & delta (dual-A) -> hd.
__global__ __launch_bounds__(256) void prep(const float* __restrict__ states,
                                            const float* __restrict__ policies,
                                            const float* __restrict__ actions,
                                            const float* __restrict__ b_sap,
                                            const float* __restrict__ ws,
                                            float* __restrict__ avact,
                                            float* __restrict__ hd) {
  __shared__ float Xa[16 * 100];
  __shared__ float Xp[16 * 100];
  __shared__ float Ea[16 * 132];
  __shared__ float Ep[16 * 132];
  __shared__ float Dd[16 * 132];
  __shared__ float WB[32 * 132];
  const int tid = threadIdx.x;
  const int b = blockIdx.x >> 2, rq = blockIdx.x & 3;
  const int r0g = b * 64 + rq * 16;

  for (int idx = tid; idx < 1024; idx += 256) {
    const int r = idx >> 6, c = idx & 63;
    const float s = states[(r0g + r) * 64 + c];
    Xa[r * 100 + c] = s;
    Xp[r * 100 + c] = s;
  }
  for (int idx = tid; idx < 512; idx += 256) {
    const int r = idx >> 5, c = idx & 31;
    Xa[r * 100 + 64 + c] = actions[(r0g + r) * 32 + c];
    Xp[r * 100 + 64 + c] = policies[(r0g + r) * 32 + c];
  }
  float aa[8] = {}, ap[8] = {};
  for (int kt = 0; kt < 3; ++kt) {
    __syncthreads();
    stageW<128, 256>(tid, ws + OFF_WSAPT + kt * 4096, WB);
    __syncthreads();
    g16_dualA<128, 256>(tid, Xa + kt * 32, Xp + kt * 32, 100, WB, 132, 32, aa, ap);
  }
  e16<128, false, true, true>(tid, aa, Ea, 132, b_sap);
  e16<128, false, true, true>(tid, ap, Ep, 132, b_sap);
  __syncthreads();
  for (int idx = tid; idx < 2048; idx += 256) {
    const int r = idx >> 7, c = idx & 127;
    Ep[r * 132 + c] -= Ea[r * 132 + c];
  }
  float av[8] = {}, dl[8] = {};
  for (int kt = 0; kt < 4; ++kt) {
    __syncthreads();
    stageW<128, 256>(tid, ws + OFF_WAVT + kt * 4096, WB);
    __syncthreads();
    g16_dualA<128, 256>(tid, Ea + kt * 32, Ep + kt * 32, 132, WB, 132, 32, av, dl);
  }
  e16<128, false, false, false>(tid, av, avact + r0g * 128, 128, nullptr);
  e16<128, false, false, false>(tid, dl, Dd, 132, nullptr);
  float ah[8] = {};
  for (int kt = 0; kt < 4; ++kt) {
    __syncthreads();
    stageW<64, 256>(tid, ws + OFF_WF1T + kt * 2048, WB);
    __syncthreads();
    if (tid < 128) g16<64, 128>(tid, Dd + kt * 32, 132, WB, 68, 32, ah);
  }
  if (tid < 128) e16<64, false, false, false>(tid, ah, hd + r0g * 64, 64, nullptr);
}

// k_eqk1: 16 rows: e = lrelu(states@WpreT+b) -> ws.E; q1,k1 dual -> ws.Q, ws.K (K feature-major)
__global__ __launch_bounds__(256) void k_eqk1(const float* __restrict__ states,
                                              const float* __restrict__ b_se_pre,
                                              float* __restrict__ ws) {
  __shared__ float Xs[16 * 68];
  __shared__ float WB[64 * 132];
  __shared__ float Er[16 * 132];
  const int tid = threadIdx.x;
  const int b = blockIdx.x >> 2, iq = blockIdx.x & 3;
  const int r0g = b * 64 + iq * 16;

  for (int idx = tid; idx < 1024; idx += 256) {
    const int r = idx >> 6, c = idx & 63;
    Xs[r * 68 + c] = states[(r0g + r) * 64 + c];
  }
  stageW<128, 256>(tid, ws + OFF_WPRET, WB);
  stageW<128, 256>(tid, ws + OFF_WPRET + 4096, WB + 32 * 132);
  __syncthreads();
  float acc[8] = {};
  g16<128, 256>(tid, Xs, 68, WB, 132, 64, acc);
  {
    const int cg = tid & 15, rg = tid >> 4, c0 = cg * 8;
#pragma unroll
    for (int jj = 0; jj < 8; ++jj) {
      float v = acc[jj] + b_se_pre[c0 + jj];
      v = (v > 0.f) ? v : NSLOPE * v;
      Er[rg * 132 + c0 + jj] = v;
      ws[OFF_E + (r0g + rg) * 128 + c0 + jj] = v;
    }
  }
  float aq[8] = {}, ak[8] = {};
  for (int kt = 0; kt < 4; ++kt) {
    __syncthreads();
    stageW<128, 256>(tid, ws + OFF_WQT + kt * 4096, WB);
    stageW<128, 256>(tid, ws + OFF_WKT + kt * 4096, WB + 32 * 132);
    __syncthreads();
    g16_dualB<128, 256>(tid, Er + kt * 32, 132, WB, WB + 32 * 132, 132, 32, aq, ak);
  }
  e16<128, false, false, false>(tid, aq, ws + OFF_Q + r0g * 128, 128, nullptr);
  e16<128, true, false, false>(tid, ak, ws + OFF_K + b * 8192 + iq * 16, 64, nullptr);
}

// k_score: s = q@kT (K feature-major), softmax in-register -> wout
__global__ __launch_bounds__(256) void k_score(const float* __restrict__ qbase,
                                               const float* __restrict__ kbase,
                                               float* __restrict__ wout) {
  __shared__ float Ks[128 * 68];  // [feature][agent]
  __shared__ float Qr[16 * 132];
  const int tid = threadIdx.x;
  const int b = blockIdx.x >> 2, iq = blockIdx.x & 3;
  const int r0g = b * 64 + iq * 16;

  for (int idx = tid; idx < 2048; idx += 256) {
    const int kk = idx >> 4, j4 = idx & 15;
    *reinterpret_cast<float4*>(&Ks[kk * 68 + j4 * 4]) =
        *reinterpret_cast<const float4*>(&kbase[b * 8192 + kk * 64 + j4 * 4]);
  }
  for (int idx = tid; idx < 512; idx += 256) {
    const int r = idx >> 5, c4 = idx & 31;
    *reinterpret_cast<float4*>(&Qr[r * 132 + c4 * 4]) =
        *reinterpret_cast<const float4*>(&qbase[(r0g + r) * 128 + c4 * 4]);
  }
  __syncthreads();
  const int j = tid & 63, iw = tid >> 6;
  float acc4[4] = {0.f, 0.f, 0.f, 0.f};
  for (int kt = 0; kt < 128; kt += 8) {
    float qv[4][8];
#pragma unroll
    for (int r = 0; r < 4; ++r) {
      *reinterpret_cast<float4*>(&qv[r][0]) =
          *reinterpret_cast<const float4*>(&Qr[(iw * 4 + r) * 132 + kt]);
      *reinterpret_cast<float4*>(&qv[r][4]) =
          *reinterpret_cast<const float4*>(&Qr[(iw * 4 + r) * 132 + kt + 4]);
    }
#pragma unroll
    for (int kk = 0; kk < 8; ++kk) {
      const float kv = Ks[(kt + kk) * 68 + j];
#pragma unroll
      for (int r = 0; r < 4; ++r) acc4[r] += qv[r][kk] * kv;
    }
  }
#pragma unroll
  for (int r = 0; r < 4; ++r) {
    float v = acc4[r] * SCALE;
    float m = v;
#pragma unroll
    for (int off = 32; off > 0; off >>= 1) m = fmaxf(m, __shfl_xor(m, off, 64));
    const float p = __expf(v - m);
    float s = p;
#pragma unroll
    for (int off = 32; off > 0; off >>= 1) s += __shfl_xor(s, off, 64);
    wout[b * 4096 + (iq * 16 + iw * 4 + r) * 64 + j] = p / s;
  }
}

// k_avseqk2: av_pre = w_pre@e ; se = lrelu(av@WseT+b) ; q2,k2 -> ws.Q, ws.K
__global__ __launch_bounds__(256) void k_avseqk2(const float* __restrict__ b_se,
                                                 const float* __restrict__ wpre,
                                                 float* __restrict__ ws) {
  __shared__ float Es[64 * 132];
  __shared__ float WB[64 * 132];
  __shared__ float Wp[16 * 68];
  __shared__ float AV[16 * 132];
  __shared__ float SEr[16 * 132];
  const int tid = threadIdx.x;
  const int b = blockIdx.x >> 2, iq = blockIdx.x & 3;
  const int r0g = b * 64 + iq * 16;

  for (int idx = tid; idx < 2048; idx += 256) {
    const int ka = idx >> 5, c4 = idx & 31;
    *reinterpret_cast<float4*>(&Es[ka * 132 + c4 * 4]) =
        *reinterpret_cast<const float4*>(&ws[OFF_E + (b * 64 + ka) * 128 + c4 * 4]);
  }
  for (int idx = tid; idx < 1024; idx += 256) {
    const int r = idx >> 6, c = idx & 63;
    Wp[r * 68 + c] = wpre[b * 4096 + (iq * 16 + r) * 64 + c];
  }
  __syncthreads();
  float acc[8] = {};
  g16<128, 256>(tid, Wp, 68, Es, 132, 64, acc);
  e16<128, false, false, false>(tid, acc, AV, 132, nullptr);
  float asE[8] = {};
  for (int kt = 0; kt < 4; ++kt) {
    __syncthreads();
    stageW<128, 256>(tid, ws + OFF_WSET + kt * 4096, WB);
    __syncthreads();
    g16<128, 256>(tid, AV + kt * 32, 132, WB, 132, 32, asE);
  }
  e16<128, false, true, true>(tid, asE, SEr, 132, b_se);
  float aq[8] = {}, ak[8] = {};
  for (int kt = 0; kt < 4; ++kt) {
    __syncthreads();
    stageW<128, 256>(tid, ws + OFF_WQT + kt * 4096, WB);
    stageW<128, 256>(tid, ws + OFF_WKT + kt * 4096, WB + 32 * 132);
    __syncthreads();
    g16_dualB<128, 256>(tid, SEr + kt * 32, 132, WB, WB + 32 * 132, 132, 32, aq, ak);
  }
  e16<128, false, false, false>(tid, aq, ws + OFF_Q + r0g * 128, 128, nullptr);
  e16<128, true, false, false>(tid, ak, ws + OFF_K + b * 8192 + iq * 16, 64, nullptr);
}

// k_nodeh: node = w@av_act ; hb = node@Wf1T -> ws (reusing K region)
__global__ __launch_bounds__(256) void k_nodeh(const float* __restrict__ wmat,
                                               const float* __restrict__ avact,
                                               float* __restrict__ ws) {
  __shared__ float AVs[64 * 132];
  __shared__ float Ws[16 * 68];
  __shared__ float NB[16 * 132];
  __shared__ float WF[32 * 68];
  const int tid = threadIdx.x;
  const int b = blockIdx.x >> 2, iq = blockIdx.x & 3;
  const int r0g = b * 64 + iq * 16;

  for (int idx = tid; idx < 2048; idx += 256) {
    const int ka = idx >> 5, c4 = idx & 31;
    *reinterpret_cast<float4*>(&AVs[ka * 132 + c4 * 4]) =
        *reinterpret_cast<const float4*>(&avact[b * 8192 + ka * 128 + c4 * 4]);
  }
  for (int idx = tid; idx < 1024; idx += 256) {
    const int r = idx >> 6, c = idx & 63;
    Ws[r * 68 + c] = wmat[b * 4096 + (iq * 16 + r) * 64 + c];
  }
  __syncthreads();
  float acc[8] = {};
  g16<128, 256>(tid, Ws, 68, AVs, 132, 64, acc);
  e16<128, false, false, false>(tid, acc, NB, 132, nullptr);
  float ah[8] = {};
  for (int kt = 0; kt < 4; ++kt) {
    __syncthreads();
    stageW<64, 256>(tid, ws + OFF_WF1T + kt * 2048, WF);
    __syncthreads();
    if (tid < 128) g16<64, 128>(tid, NB + kt * 32, 132, WF, 68, 32, ah);
  }
  if (tid < 128) e16<64, false, false, false>(tid, ah, ws + OFF_K + r0g * 64, 64, nullptr);
}

// k_head: value[b,i,j] = sum_f lrelu(hb[i,f] + w[i,j]*hd[j,f]) * Wf2[f]
__global__ __launch_bounds__(256) void k_head(const float* __restrict__ wmat,
                                              const float* __restrict__ Wf2g,
                                              const float* __restrict__ hbase,
                                              const float* __restrict__ hdbase,
                                              float* __restrict__ out) {
  __shared__ float Hd[64 * 69];
  __shared__ float Hb[16 * 68];
  __shared__ float Wsr[16 * 68];
  __shared__ float Wf2s[64];
  const int tid = threadIdx.x;
  const int b = blockIdx.x >> 2, iq = blockIdx.x & 3;
  const int r0g = b * 64 + iq * 16;

  for (int idx = tid; idx < 4096; idx += 256) {
    const int jj = idx >> 6, f = idx & 63;
    Hd[jj * 69 + f] = hdbase[b * 4096 + idx];
  }
  for (int idx = tid; idx < 256; idx += 256) {
    const int r = idx >> 4, c4 = idx & 15;
    *reinterpret_cast<float4*>(&Hb[r * 68 + c4 * 4]) =
        *reinterpret_cast<const float4*>(&hbase[(r0g + r) * 64 + c4 * 4]);
  }
  for (int idx = tid; idx < 1024; idx += 256) {
    const int r = idx >> 6, c = idx & 63;
    Wsr[r * 68 + c] = wmat[b * 4096 + (iq * 16 + r) * 64 + c];
  }
  if (tid < 64) Wf2s[tid] = Wf2g[tid];
  __syncthreads();
  const int j = tid & 63, iw = tid >> 6;
  float wv[4], a4[4] = {0.f, 0.f, 0.f, 0.f};
#pragma unroll
  for (int r = 0; r < 4; ++r) wv[r] = Wsr[(iw * 4 + r) * 68 + j];
  for (int f = 0; f < 64; ++f) {
    const float hdv = Hd[j * 69 + f];
    const float wf = Wf2s[f];
#pragma unroll
    for (int r = 0; r < 4; ++r) {
      float t = Hb[(iw * 4 + r) * 68 + f] + wv[r] * hdv;
      t = (t > 0.f) ? t : NSLOPE * t;
      a4[r] += t * wf;
    }
  }
#pragma unroll
  for (int r = 0; r < 4; ++r)
    out[(b * 64 + iq * 16 + iw * 4 + r) * 64 + j] = a4[r];
}

// ===================== fallback path (round-2, proven, 3.54 MB ws) =====================

__global__ __launch_bounds__(512) void stage12(const float* __restrict__ states,
                                               const float* __restrict__ b_se_pre,
                                               const float* __restrict__ b_se,
                                               const float* __restrict__ ws,
                                               float* __restrict__ out) {
  __shared__ float sA[64 * 68];
  __shared__ float sE[8704];
  __shared__ float sQ[8704];
  __shared__ float sK[8704];
  const int b = blockIdx.x, tid = threadIdx.x;

  for (int idx = tid; idx < 4096; idx += 512) {
    const int i = idx >> 6, c = idx & 63;
    sA[i * 68 + c] = states[(b * 64 + i) * 64 + c];
  }
  __syncthreads();
  {
    float acc[2][8]; zero_acc(acc);
    gemm_accum<128, 512, 2>(tid, sA, 68, ws + OFF_WPRET, 128, 64, acc);
    epilogue<128, 512, 2, false, true, true>(tid, acc, sE, 132, b_se_pre);
  }
  __syncthreads();
  {
    float acc[2][8]; zero_acc(acc);
    gemm_accum<128, 512, 2>(tid, sE, 132, ws + OFF_WQT, 128, 128, acc);
    epilogue<128, 512, 2, false, false, false>(tid, acc, sQ, 132, nullptr);
  }
  {
    float acc[2][8]; zero_acc(acc);
    gemm_accum<128, 512, 2>(tid, sE, 132, ws + OFF_WKT, 128, 128, acc);
    epilogue<128, 512, 2, true, false, false>(tid, acc, sK, 68, nullptr);
  }
  __syncthreads();
  {
    float acc[1][8]; zero_acc(acc);
    gemm_accum<64, 512, 1>(tid, sQ, 132, sK, 68, 128, acc);
    epilogue<64, 512, 1, false, false, false>(tid, acc, sA, 68, nullptr);
  }
  __syncthreads();
  softmax64<512>(tid, sA, SCALE, out + BNN + b * 4096);
  __syncthreads();
  {
    float acc[2][8]; zero_acc(acc);
    gemm_accum<128, 512, 2>(tid, sA, 68, sE, 132, 64, acc);
    epilogue<128, 512, 2, false, false, false>(tid, acc, sQ, 132, nullptr);
  }
  __syncthreads();
  {
    float acc[2][8]; zero_acc(acc);
    gemm_accum<128, 512, 2>(tid, sQ, 132, ws + OFF_WSET, 128, 128, acc);
    epilogue<128, 512, 2, false, true, true>(tid, acc, sK, 132, b_se);
  }
  __syncthreads();
  {
    float acc[2][8]; zero_acc(acc);
    gemm_accum<128, 512, 2>(tid, sK, 132, ws + OFF_WQT, 128, 128, acc);
    epilogue<128, 512, 2, false, false, false>(tid, acc, sE, 132, nullptr);
  }
  {
    float acc[2][8]; zero_acc(acc);
    gemm_accum<128, 512, 2>(tid, sK, 132, ws + OFF_WKT, 128, 128, acc);
    epilogue<128, 512, 2, true, false, false>(tid, acc, sQ, 68, nullptr);
  }
  __syncthreads();
  {
    float acc[1][8]; zero_acc(acc);
    gemm_accum<64, 512, 1>(tid, sE, 132, sQ, 68, 128, acc);
    epilogue<64, 512, 1, false, false, false>(tid, acc, sA, 68, nullptr);
  }
  __syncthreads();
  softmax64<512>(tid, sA, SCALE, out + 2 * BNN + b * 4096);
}

__global__ __launch_bounds__(512) void finale(const float* __restrict__ Wf2g,
                                              const float* __restrict__ ws,
                                              const float* __restrict__ avact,
                                              const float* __restrict__ hdbase,
                                              float* __restrict__ out) {
  __shared__ float wS[64 * 68];
  __shared__ float NB[64 * 132];
  __shared__ float Hb[64 * 68];
  __shared__ float Hd[64 * 69];
  __shared__ float Wf2s[64];
  const int b = blockIdx.x, tid = threadIdx.x;

  const float* wg = out + 2 * BNN + b * 4096;
  for (int idx = tid; idx < 4096; idx += 512)
    wS[(idx >> 6) * 68 + (idx & 63)] = wg[idx];
  for (int idx = tid; idx < 4096; idx += 512)
    Hd[(idx >> 6) * 69 + (idx & 63)] = hdbase[b * 4096 + idx];
  if (tid < 64) Wf2s[tid] = Wf2g[tid];
  __syncthreads();
  {
    float acc[2][8]; zero_acc(acc);
    gemm_accum<128, 512, 2>(tid, wS, 68, avact + b * 8192, 128, 64, acc);
    epilogue<128, 512, 2, false, false, false>(tid, acc, NB, 132, nullptr);
  }
  __syncthreads();
  {
    float acc[1][8]; zero_acc(acc);
    gemm_accum<64, 512, 1>(tid, NB, 132, ws + OFF_WF1T, 64, 128, acc);
    epilogue<64, 512, 1, false, false, false>(tid, acc, Hb, 68, nullptr);
  }
  __syncthreads();
  const int j = tid & 63, iw = tid >> 6;
  float wv[8], acc8[8];
#pragma unroll
  for (int ii = 0; ii < 8; ++ii) {
    wv[ii] = wS[(iw * 8 + ii) * 68 + j];
    acc8[ii] = 0.f;
  }
  for (int f = 0; f < 64; ++f) {
    const float hdv = Hd[j * 69 + f];
    const float wf = Wf2s[f];
#pragma unroll
    for (int ii = 0; ii < 8; ++ii) {
      float t = Hb[(iw * 8 + ii) * 68 + f] + wv[ii] * hdv;
      t = (t > 0.f) ? t : NSLOPE * t;
      acc8[ii] += t * wf;
    }
  }
#pragma unroll
  for (int ii = 0; ii < 8; ++ii)
    out[(b * 64 + iw * 8 + ii) * 64 + j] = acc8[ii];
}

extern "C" void kernel_launch(void* const* d_in, const int* in_sizes, int n_in,
                              void* d_out, int out_size, void* d_ws, size_t ws_size,
                              hipStream_t stream) {
  const float* states   = (const float*)d_in[0];
  const float* policies = (const float*)d_in[1];
  const float* actions  = (const float*)d_in[2];
  const float* W_se_pre = (const float*)d_in[3];
  const float* b_se_pre = (const float*)d_in[4];
  const float* W_key    = (const float*)d_in[5];
  const float* W_query  = (const float*)d_in[6];
  const float* W_se     = (const float*)d_in[7];
  const float* b_se     = (const float*)d_in[8];
  const float* W_sap    = (const float*)d_in[9];
  const float* b_sap    = (const float*)d_in[10];
  const float* W_av     = (const float*)d_in[11];
  const float* W_f1     = (const float*)d_in[12];
  const float* W_f2     = (const float*)d_in[13];
  float* out = (float*)d_out;
  float* ws  = (float*)d_ws;

  hipLaunchKernelGGL(transpose_all, dim3(64, 7), dim3(256), 0, stream,
                     W_se_pre, W_query, W_key, W_se, W_sap, W_av, W_f1, ws);

  if (ws_size >= NEED_BYTES) {
    hipLaunchKernelGGL(prep, dim3(256), dim3(256), 0, stream,
                       states, policies, actions, b_sap, ws,
                       ws + OFF_AVACT, ws + OFF_HD);
    hipLaunchKernelGGL(k_eqk1, dim3(256), dim3(256), 0, stream, states, b_se_pre, ws);
    hipLaunchKernelGGL(k_score, dim3(256), dim3(256), 0, stream,
                       ws + OFF_Q, ws + OFF_K, out + BNN);
    hipLaunchKernelGGL(k_avseqk2, dim3(256), dim3(256), 0, stream, b_se, out + BNN, ws);
    hipLaunchKernelGGL(k_score, dim3(256), dim3(256), 0, stream,
                       ws + OFF_Q, ws + OFF_K, out + 2 * BNN);
    hipLaunchKernelGGL(k_nodeh, dim3(256), dim3(256), 0, stream,
                       out + 2 * BNN, ws + OFF_AVACT, ws);
    hipLaunchKernelGGL(k_head, dim3(256), dim3(256), 0, stream,
                       out + 2 * BNN, W_f2, ws + OFF_K, ws + OFF_HD, out);
  } else {
    hipLaunchKernelGGL(prep, dim3(256), dim3(256), 0, stream,
                       states, policies, actions, b_sap, ws,
                       ws + OFF_AVACT_F, ws + OFF_HD_F);
    hipLaunchKernelGGL(stage12, dim3(64), dim3(512), 0, stream,
                       states, b_se_pre, b_se, ws, out);
    hipLaunchKernelGGL(finale, dim3(64), dim3(512), 0, stream,
                       W_f2, ws, ws + OFF_AVACT_F, ws + OFF_HD_F, out);
  }
}

// Round 4
// 124.120 us; speedup vs baseline: 5.1344x; 1.0816x over previous
//
#include <hip/hip_runtime.h>

#define DEVFN __device__ __forceinline__

constexpr int BNN = 64 * 64 * 64;              // 262144 per output tensor
constexpr float SCALE = 0.08838834764831845f;  // 1/sqrt(128)
constexpr float NSLOPE = 0.01f;

// ---- ws layout (floats) ----
constexpr int OFF_WPRET = 0;       // [64][128]
constexpr int OFF_WQT   = 8192;    // [128][128]
constexpr int OFF_WKT   = 24576;   // [128][128]
constexpr int OFF_WSET  = 40960;   // [128][128]
constexpr int OFF_WSAPT = 57344;   // [96][128]
constexpr int OFF_WAVT  = 69632;   // [128][128]
constexpr int OFF_WF1T  = 86016;   // [128][64]
// wide-pipeline intermediates
constexpr int OFF_E     = 98304;    // [4096][128]
constexpr int OFF_Q     = 622592;   // [4096][128]  q1 then q2 (same-row aliasing, safe)
constexpr int OFF_K1    = 1146880;  // [B][128][64] feature-major
constexpr int OFF_K2    = 1671168;  // [B][128][64] feature-major
constexpr int OFF_AVACT = 2195456;  // [B][64][128]
constexpr int OFF_HD    = 2719744;  // [B][64][64]
constexpr size_t NEED_BYTES = (size_t)(OFF_HD + 262144) * 4;  // ~11.93 MB
// fallback layout (3.54 MB, proven)
constexpr int OFF_AVACT_F = 98304;
constexpr int OFF_HD_F    = 622592;

// ===================== 8-row GEMM helpers (1 row x 4 cols per thread) =====================
// A: [8][lda] in LDS (broadcast reads). B: [K][ldb] GLOBAL (coalesced 512B/wave rows).

template<int NCOLS, int NT>
DEVFN void g4(int tid, const float* __restrict__ A, int lda,
              const float* __restrict__ B, int ldb, int K, float (&acc)[4]) {
  constexpr int NCG = NCOLS / 4;
  const int cg = tid % NCG, rg = tid / NCG;
  const int c0 = cg * 4;
#pragma unroll 4
  for (int k = 0; k < K; ++k) {
    const float4 b0 = *reinterpret_cast<const float4*>(&B[k * ldb + c0]);
    const float a = A[rg * lda + k];
    acc[0] += a * b0.x; acc[1] += a * b0.y; acc[2] += a * b0.z; acc[3] += a * b0.w;
  }
}

template<int NCOLS, int NT>
DEVFN void g4_dualA(int tid, const float* __restrict__ A0, const float* __restrict__ A1,
                    int lda, const float* __restrict__ B, int ldb, int K,
                    float (&a0)[4], float (&a1)[4]) {
  constexpr int NCG = NCOLS / 4;
  const int cg = tid % NCG, rg = tid / NCG;
  const int c0 = cg * 4;
#pragma unroll 4
  for (int k = 0; k < K; ++k) {
    const float4 b0 = *reinterpret_cast<const float4*>(&B[k * ldb + c0]);
    const float x = A0[rg * lda + k];
    const float y = A1[rg * lda + k];
    a0[0] += x * b0.x; a0[1] += x * b0.y; a0[2] += x * b0.z; a0[3] += x * b0.w;
    a1[0] += y * b0.x; a1[1] += y * b0.y; a1[2] += y * b0.z; a1[3] += y * b0.w;
  }
}

template<int NCOLS, int NT>
DEVFN void g4_dualB(int tid, const float* __restrict__ A, int lda,
                    const float* __restrict__ B0, const float* __restrict__ B1,
                    int ldb, int K, float (&a0)[4], float (&a1)[4]) {
  constexpr int NCG = NCOLS / 4;
  const int cg = tid % NCG, rg = tid / NCG;
  const int c0 = cg * 4;
#pragma unroll 4
  for (int k = 0; k < K; ++k) {
    const float4 p0 = *reinterpret_cast<const float4*>(&B0[k * ldb + c0]);
    const float4 q0 = *reinterpret_cast<const float4*>(&B1[k * ldb + c0]);
    const float a = A[rg * lda + k];
    a0[0] += a * p0.x; a0[1] += a * p0.y; a0[2] += a * p0.z; a0[3] += a * p0.w;
    a1[0] += a * q0.x; a1[1] += a * q0.y; a1[2] += a * q0.z; a1[3] += a * q0.w;
  }
}

template<int NCOLS, bool ACT, bool HASB>
DEVFN void e4g(int tid, float (&acc)[4], float* __restrict__ O, int ldo,
               const float* __restrict__ bias) {
  constexpr int NCG = NCOLS / 4;
  const int cg = tid % NCG, rg = tid / NCG, c0 = cg * 4;
  float t[4];
#pragma unroll
  for (int i = 0; i < 4; ++i) {
    float x = acc[i];
    if constexpr (HASB) x += bias[c0 + i];
    if constexpr (ACT) x = (x > 0.f) ? x : NSLOPE * x;
    t[i] = x;
  }
  float4 v; v.x = t[0]; v.y = t[1]; v.z = t[2]; v.w = t[3];
  *reinterpret_cast<float4*>(&O[rg * ldo + c0]) = v;
}

template<int NCOLS>
DEVFN void e4t(int tid, float (&acc)[4], float* __restrict__ O, int ldo) {
  constexpr int NCG = NCOLS / 4;
  const int cg = tid % NCG, rg = tid / NCG, c0 = cg * 4;
#pragma unroll
  for (int i = 0; i < 4; ++i) O[(c0 + i) * ldo + rg] = acc[i];
}

// Score + softmax for an 8-row block: scores = q @ K^T (K feature-major, staged in
// two 16KB halves), softmax in-register (64-lane shfl). Writes Wp (pitch 68) + gout.
DEVFN void score8(int tid, const float* __restrict__ qblk, const float* __restrict__ kb,
                  float* Ks, float* Wp, float* __restrict__ gout) {
  const int j = tid & 63, iw = tid >> 6;
  float acc2[2] = {0.f, 0.f};
  for (int h = 0; h < 2; ++h) {
    for (int idx = tid; idx < 1024; idx += 256) {
      const int kk = idx >> 4, j4 = idx & 15;
      *reinterpret_cast<float4*>(&Ks[kk * 64 + j4 * 4]) =
          *reinterpret_cast<const float4*>(&kb[(h * 64 + kk) * 64 + j4 * 4]);
    }
    __syncthreads();
#pragma unroll 2
    for (int kt = 0; kt < 64; kt += 8) {
      float qv[2][8];
#pragma unroll
      for (int r = 0; r < 2; ++r) {
        *reinterpret_cast<float4*>(&qv[r][0]) =
            *reinterpret_cast<const float4*>(&qblk[(iw * 2 + r) * 128 + h * 64 + kt]);
        *reinterpret_cast<float4*>(&qv[r][4]) =
            *reinterpret_cast<const float4*>(&qblk[(iw * 2 + r) * 128 + h * 64 + kt + 4]);
      }
#pragma unroll
      for (int kk = 0; kk < 8; ++kk) {
        const float kv = Ks[(kt + kk) * 64 + j];
        acc2[0] += qv[0][kk] * kv;
        acc2[1] += qv[1][kk] * kv;
      }
    }
    __syncthreads();
  }
#pragma unroll
  for (int r = 0; r < 2; ++r) {
    float v = acc2[r] * SCALE;
    float m = v;
#pragma unroll
    for (int off = 32; off > 0; off >>= 1) m = fmaxf(m, __shfl_xor(m, off, 64));
    const float p = __expf(v - m);
    float s = p;
#pragma unroll
    for (int off = 32; off > 0; off >>= 1) s += __shfl_xor(s, off, 64);
    const float w = p / s;
    Wp[(iw * 2 + r) * 68 + j] = w;
    gout[(iw * 2 + r) * 64 + j] = w;
  }
}

// ===================== legacy helpers (fallback path only) =====================

template<int R>
DEVFN void zero_acc(float (&a)[R][8]) {
#pragma unroll
  for (int i = 0; i < R; ++i)
#pragma unroll
    for (int j = 0; j < 8; ++j) a[i][j] = 0.f;
}

template<int NCOLS, int NT, int RPT>
DEVFN void gemm_accum(int tid, const float* __restrict__ A, int lda,
                      const float* __restrict__ B, int ldb, int K,
                      float (&acc)[RPT][8]) {
  constexpr int NCG = NCOLS / 8;
  const int cg = tid % NCG, rg = tid / NCG;
  const int r0 = rg * RPT, c0 = cg * 8;
#pragma unroll 4
  for (int k = 0; k < K; ++k) {
    const float4 b0 = *reinterpret_cast<const float4*>(&B[k * ldb + c0]);
    const float4 b1 = *reinterpret_cast<const float4*>(&B[k * ldb + c0 + 4]);
#pragma unroll
    for (int i = 0; i < RPT; ++i) {
      const float a = A[(r0 + i) * lda + k];
      acc[i][0] += a * b0.x; acc[i][1] += a * b0.y;
      acc[i][2] += a * b0.z; acc[i][3] += a * b0.w;
      acc[i][4] += a * b1.x; acc[i][5] += a * b1.y;
      acc[i][6] += a * b1.z; acc[i][7] += a * b1.w;
    }
  }
}

template<int NCOLS, int NT, int RPT, bool TRANS, bool ACT, bool HASB>
DEVFN void epilogue(int tid, float (&acc)[RPT][8], float* __restrict__ O, int ldo,
                    const float* __restrict__ bias) {
  constexpr int NCG = NCOLS / 8;
  const int cg = tid % NCG, rg = tid / NCG;
  const int r0 = rg * RPT, c0 = cg * 8;
#pragma unroll
  for (int jj = 0; jj < 8; ++jj) {
    float bv = 0.f;
    if constexpr (HASB) bv = bias[c0 + jj];
#pragma unroll
    for (int i = 0; i < RPT; ++i) {
      float v = acc[i][jj] + bv;
      if constexpr (ACT) v = (v > 0.f) ? v : NSLOPE * v;
      if constexpr (TRANS) O[(c0 + jj) * ldo + (r0 + i)] = v;
      else                 O[(r0 + i) * ldo + (c0 + jj)] = v;
    }
  }
}

template<int NT>
DEVFN void softmax64(int tid, float* S, float scale, float* __restrict__ gout) {
  const int lane = tid & 63, wv = tid >> 6;
  for (int i = wv; i < 64; i += NT / 64) {
    float v = S[i * 68 + lane] * scale;
    float m = v;
#pragma unroll
    for (int off = 32; off > 0; off >>= 1) m = fmaxf(m, __shfl_xor(m, off, 64));
    const float p = __expf(v - m);
    float s = p;
#pragma unroll
    for (int off = 32; off > 0; off >>= 1) s += __shfl_xor(s, off, 64);
    const float r = p / s;
    S[i * 68 + lane] = r;
    gout[i * 64 + lane] = r;
  }
}

// ===================== kernels =====================

__global__ void transpose_all(const float* __restrict__ Wpre, const float* __restrict__ Wq,
                              const float* __restrict__ Wk, const float* __restrict__ Wse,
                              const float* __restrict__ Wsap, const float* __restrict__ Wav,
                              const float* __restrict__ Wf1, float* __restrict__ ws) {
  const int m = blockIdx.y;
  const float* src; int Cout, K, off;
  switch (m) {
    case 0: src = Wpre; Cout = 128; K = 64;  off = OFF_WPRET; break;
    case 1: src = Wq;   Cout = 128; K = 128; off = OFF_WQT;   break;
    case 2: src = Wk;   Cout = 128; K = 128; off = OFF_WKT;   break;
    case 3: src = Wse;  Cout = 128; K = 128; off = OFF_WSET;  break;
    case 4: src = Wsap; Cout = 128; K = 96;  off = OFF_WSAPT; break;
    case 5: src = Wav;  Cout = 128; K = 128; off = OFF_WAVT;  break;
    default: src = Wf1; Cout = 64;  K = 128; off = OFF_WF1T;  break;
  }
  const int idx = blockIdx.x * 256 + threadIdx.x;
  if (idx < Cout * K) {
    const int c = idx / K, k = idx - c * K;
    ws[off + k * Cout + c] = src[idx];
  }
}

// P1: 512 blocks x 256 thr, 8 rows each. prep (E_act/E_pol -> av_act, delta -> hd)
// and, if WIDE, e -> q1/k1.
template<bool WIDE>
__global__ __launch_bounds__(256) void P1(const float* __restrict__ states,
                                          const float* __restrict__ policies,
                                          const float* __restrict__ actions,
                                          const float* __restrict__ b_sap,
                                          const float* __restrict__ b_se_pre,
                                          float* __restrict__ ws,
                                          float* __restrict__ avact,
                                          float* __restrict__ hd) {
  __shared__ float Xa[8 * 100];
  __shared__ float Xp[8 * 100];
  __shared__ float Ea[8 * 132];
  __shared__ float Ep[8 * 132];
  __shared__ float Dd[8 * 132];
  __shared__ float Er[8 * 132];
  const int tid = threadIdx.x;
  const int b = blockIdx.x >> 3, rq = blockIdx.x & 7;
  const int r0g = b * 64 + rq * 8;

  for (int idx = tid; idx < 512; idx += 256) {
    const int r = idx >> 6, c = idx & 63;
    const float s = states[(r0g + r) * 64 + c];
    Xa[r * 100 + c] = s;
    Xp[r * 100 + c] = s;
  }
  {
    const int r = tid >> 5, c = tid & 31;
    Xa[r * 100 + 64 + c] = actions[(r0g + r) * 32 + c];
    Xp[r * 100 + 64 + c] = policies[(r0g + r) * 32 + c];
  }
  __syncthreads();
  { // E_act, E_pol (dual-A over Wsap^T)
    float aa[4] = {}, ap[4] = {};
    g4_dualA<128, 256>(tid, Xa, Xp, 100, ws + OFF_WSAPT, 128, 96, aa, ap);
    e4g<128, true, true>(tid, aa, Ea, 132, b_sap);
    e4g<128, true, true>(tid, ap, Ep, 132, b_sap);
  }
  __syncthreads();
  for (int idx = tid; idx < 1024; idx += 256) {
    const int r = idx >> 7, c = idx & 127;
    Ep[r * 132 + c] -= Ea[r * 132 + c];
  }
  __syncthreads();
  { // av_act (global), delta (LDS)
    float av[4] = {}, dl[4] = {};
    g4_dualA<128, 256>(tid, Ea, Ep, 132, ws + OFF_WAVT, 128, 128, av, dl);
    e4g<128, false, false>(tid, av, avact + r0g * 128, 128, nullptr);
    e4g<128, false, false>(tid, dl, Dd, 132, nullptr);
  }
  __syncthreads();
  if (tid < 128) { // hd = delta @ Wf1^T
    float ah[4] = {};
    g4<64, 128>(tid, Dd, 132, ws + OFF_WF1T, 64, 128, ah);
    e4g<64, false, false>(tid, ah, hd + r0g * 64, 64, nullptr);
  }
  if constexpr (WIDE) {
    { // e = lrelu(states @ Wpre^T + b): -> Er LDS + ws.E global
      float ae[4] = {};
      g4<128, 256>(tid, Xa, 100, ws + OFF_WPRET, 128, 64, ae);
      const int cg = tid & 31, rg = tid >> 5, c0 = cg * 4;
      float t[4];
#pragma unroll
      for (int i = 0; i < 4; ++i) {
        float x = ae[i] + b_se_pre[c0 + i];
        t[i] = (x > 0.f) ? x : NSLOPE * x;
      }
      float4 v; v.x = t[0]; v.y = t[1]; v.z = t[2]; v.w = t[3];
      *reinterpret_cast<float4*>(&Er[rg * 132 + c0]) = v;
      *reinterpret_cast<float4*>(&ws[OFF_E + (r0g + rg) * 128 + c0]) = v;
    }
    __syncthreads();
    { // q1 (row-major), k1 (feature-major)
      float aq[4] = {}, ak[4] = {};
      g4_dualB<128, 256>(tid, Er, 132, ws + OFF_WQT, ws + OFF_WKT, 128, 128, aq, ak);
      e4g<128, false, false>(tid, aq, ws + OFF_Q + r0g * 128, 128, nullptr);
      e4t<128>(tid, ak, ws + OFF_K1 + b * 8192 + rq * 8, 64);
    }
  }
}

// P3: 512 blocks. score1+softmax -> w_pre; av_pre = w_pre@e; se; q2/k2.
__global__ __launch_bounds__(256) void P3(const float* __restrict__ b_se,
                                          float* __restrict__ ws,
                                          float* __restrict__ out) {
  __shared__ float Ks[64 * 64];
  __shared__ float Wp[8 * 68];
  __shared__ float AV[8 * 132];
  __shared__ float SEr[8 * 132];
  const int tid = threadIdx.x;
  const int b = blockIdx.x >> 3, iq = blockIdx.x & 7;
  const int r0g = b * 64 + iq * 8;

  score8(tid, ws + OFF_Q + r0g * 128, ws + OFF_K1 + b * 8192, Ks, Wp,
         out + BNN + b * 4096 + iq * 512);
  __syncthreads();
  { // av_pre = w_pre @ e  (B = e rows of this batch, global)
    float a4[4] = {};
    g4<128, 256>(tid, Wp, 68, ws + OFF_E + b * 8192, 128, 64, a4);
    e4g<128, false, false>(tid, a4, AV, 132, nullptr);
  }
  __syncthreads();
  { // se = lrelu(av @ Wse^T + b_se)
    float a4[4] = {};
    g4<128, 256>(tid, AV, 132, ws + OFF_WSET, 128, 128, a4);
    e4g<128, true, true>(tid, a4, SEr, 132, b_se);
  }
  __syncthreads();
  { // q2 (aliases q1 rows), k2 (separate feature-major region)
    float aq[4] = {}, ak[4] = {};
    g4_dualB<128, 256>(tid, SEr, 132, ws + OFF_WQT, ws + OFF_WKT, 128, 128, aq, ak);
    e4g<128, false, false>(tid, aq, ws + OFF_Q + r0g * 128, 128, nullptr);
    e4t<128>(tid, ak, ws + OFF_K2 + b * 8192 + iq * 8, 64);
  }
}

// P4: 512 blocks. score2 -> w; node = w@av_act; hb = node@Wf1^T; head -> value.
__global__ __launch_bounds__(256) void P4(const float* __restrict__ Wf2g,
                                          float* __restrict__ ws,
                                          float* __restrict__ out) {
  __shared__ float Ks[64 * 64];
  __shared__ float Wp[8 * 68];
  __shared__ float NB[8 * 132];
  __shared__ float Hb[8 * 68];
  __shared__ float Hd[64 * 69];
  __shared__ float Wf2s[64];
  const int tid = threadIdx.x;
  const int b = blockIdx.x >> 3, iq = blockIdx.x & 7;
  const int r0g = b * 64 + iq * 8;

  for (int idx = tid; idx < 4096; idx += 256)
    Hd[(idx >> 6) * 69 + (idx & 63)] = ws[OFF_HD + b * 4096 + idx];
  if (tid < 64) Wf2s[tid] = Wf2g[tid];

  score8(tid, ws + OFF_Q + r0g * 128, ws + OFF_K2 + b * 8192, Ks, Wp,
         out + 2 * BNN + b * 4096 + iq * 512);
  __syncthreads();
  { // node = w @ av_act
    float a4[4] = {};
    g4<128, 256>(tid, Wp, 68, ws + OFF_AVACT + b * 8192, 128, 64, a4);
    e4g<128, false, false>(tid, a4, NB, 132, nullptr);
  }
  __syncthreads();
  if (tid < 128) { // hb = node @ Wf1^T (no activation)
    float ah[4] = {};
    g4<64, 128>(tid, NB, 132, ws + OFF_WF1T, 64, 128, ah);
    e4g<64, false, false>(tid, ah, Hb, 68, nullptr);
  }
  __syncthreads();
  // head: value[i][j] = sum_f lrelu(hb[i,f] + w[i,j]*hd[j,f]) * Wf2[f]
  const int j = tid & 63, iw = tid >> 6;
  float wv[2], a2[2] = {0.f, 0.f};
#pragma unroll
  for (int r = 0; r < 2; ++r) wv[r] = Wp[(iw * 2 + r) * 68 + j];
  for (int f = 0; f < 64; ++f) {
    const float hdv = Hd[j * 69 + f];
    const float wf = Wf2s[f];
#pragma unroll
    for (int r = 0; r < 2; ++r) {
      float t = Hb[(iw * 2 + r) * 68 + f] + wv[r] * hdv;
      t = (t > 0.f) ? t : NSLOPE * t;
      a2[r] += t * wf;
    }
  }
#pragma unroll
  for (int r = 0; r < 2; ++r)
    out[(r0g + iw * 2 + r) * 64 + j] = a2[r];
}

// ===================== fallback path (proven, 3.54 MB ws) =====================

__global__ __launch_bounds__(512) void stage12(const float* __restrict__ states,
                                               const float* __restrict__ b_se_pre,
                                               const float* __restrict__ b_se,
                                               const float* __restrict__ ws,
                                               float* __restrict__ out) {
  __shared__ float sA[64 * 68];
  __shared__ float sE[8704];
  __shared__ float sQ[8704];
  __shared__ float sK[8704];
  const int b = blockIdx.x, tid = threadIdx.x;

  for (int idx = tid; idx < 4096; idx += 512) {
    const int i = idx >> 6, c = idx & 63;
    sA[i * 68 + c] = states[(b * 64 + i) * 64 + c];
  }
  __syncthreads();
  {
    float acc[2][8]; zero_acc(acc);
    gemm_accum<128, 512, 2>(tid, sA, 68, ws + OFF_WPRET, 128, 64, acc);
    epilogue<128, 512, 2, false, true, true>(tid, acc, sE, 132, b_se_pre);
  }
  __syncthreads();
  {
    float acc[2][8]; zero_acc(acc);
    gemm_accum<128, 512, 2>(tid, sE, 132, ws + OFF_WQT, 128, 128, acc);
    epilogue<128, 512, 2, false, false, false>(tid, acc, sQ, 132, nullptr);
  }
  {
    float acc[2][8]; zero_acc(acc);
    gemm_accum<128, 512, 2>(tid, sE, 132, ws + OFF_WKT, 128, 128, acc);
    epilogue<128, 512, 2, true, false, false>(tid, acc, sK, 68, nullptr);
  }
  __syncthreads();
  {
    float acc[1][8]; zero_acc(acc);
    gemm_accum<64, 512, 1>(tid, sQ, 132, sK, 68, 128, acc);
    epilogue<64, 512, 1, false, false, false>(tid, acc, sA, 68, nullptr);
  }
  __syncthreads();
  softmax64<512>(tid, sA, SCALE, out + BNN + b * 4096);
  __syncthreads();
  {
    float acc[2][8]; zero_acc(acc);
    gemm_accum<128, 512, 2>(tid, sA, 68, sE, 132, 64, acc);
    epilogue<128, 512, 2, false, false, false>(tid, acc, sQ, 132, nullptr);
  }
  __syncthreads();
  {
    float acc[2][8]; zero_acc(acc);
    gemm_accum<128, 512, 2>(tid, sQ, 132, ws + OFF_WSET, 128, 128, acc);
    epilogue<128, 512, 2, false, true, true>(tid, acc, sK, 132, b_se);
  }
  __syncthreads();
  {
    float acc[2][8]; zero_acc(acc);
    gemm_accum<128, 512, 2>(tid, sK, 132, ws + OFF_WQT, 128, 128, acc);
    epilogue<128, 512, 2, false, false, false>(tid, acc, sE, 132, nullptr);
  }
  {
    float acc[2][8]; zero_acc(acc);
    gemm_accum<128, 512, 2>(tid, sK, 132, ws + OFF_WKT, 128, 128, acc);
    epilogue<128, 512, 2, true, false, false>(tid, acc, sQ, 68, nullptr);
  }
  __syncthreads();
  {
    float acc[1][8]; zero_acc(acc);
    gemm_accum<64, 512, 1>(tid, sE, 132, sQ, 68, 128, acc);
    epilogue<64, 512, 1, false, false, false>(tid, acc, sA, 68, nullptr);
  }
  __syncthreads();
  softmax64<512>(tid, sA, SCALE, out + 2 * BNN + b * 4096);
}

__global__ __launch_bounds__(512) void finale(const float* __restrict__ Wf2g,
                                              const float* __restrict__ ws,
                                              const float* __restrict__ avact,
                                              const float* __restrict__ hdbase,
                                              float* __restrict__ out) {
  __shared__ float wS[64 * 68];
  __shared__ float NB[64 * 132];
  __shared__ float Hb[64 * 68];
  __shared__ float Hd[64 * 69];
  __shared__ float Wf2s[64];
  const int b = blockIdx.x, tid = threadIdx.x;

  const float* wg = out + 2 * BNN + b * 4096;
  for (int idx = tid; idx < 4096; idx += 512)
    wS[(idx >> 6) * 68 + (idx & 63)] = wg[idx];
  for (int idx = tid; idx < 4096; idx += 512)
    Hd[(idx >> 6) * 69 + (idx & 63)] = hdbase[b * 4096 + idx];
  if (tid < 64) Wf2s[tid] = Wf2g[tid];
  __syncthreads();
  {
    float acc[2][8]; zero_acc(acc);
    gemm_accum<128, 512, 2>(tid, wS, 68, avact + b * 8192, 128, 64, acc);
    epilogue<128, 512, 2, false, false, false>(tid, acc, NB, 132, nullptr);
  }
  __syncthreads();
  {
    float acc[1][8]; zero_acc(acc);
    gemm_accum<64, 512, 1>(tid, NB, 132, ws + OFF_WF1T, 64, 128, acc);
    epilogue<64, 512, 1, false, false, false>(tid, acc, Hb, 68, nullptr);
  }
  __syncthreads();
  const int j = tid & 63, iw = tid >> 6;
  float wv[8], acc8[8];
#pragma unroll
  for (int ii = 0; ii < 8; ++ii) {
    wv[ii] = wS[(iw * 8 + ii) * 68 + j];
    acc8[ii] = 0.f;
  }
  for (int f = 0; f < 64; ++f) {
    const float hdv = Hd[j * 69 + f];
    const float wf = Wf2s[f];
#pragma unroll
    for (int ii = 0; ii < 8; ++ii) {
      float t = Hb[(iw * 8 + ii) * 68 + f] + wv[ii] * hdv;
      t = (t > 0.f) ? t : NSLOPE * t;
      acc8[ii] += t * wf;
    }
  }
#pragma unroll
  for (int ii = 0; ii < 8; ++ii)
    out[(b * 64 + iw * 8 + ii) * 64 + j] = acc8[ii];
}

extern "C" void kernel_launch(void* const* d_in, const int* in_sizes, int n_in,
                              void* d_out, int out_size, void* d_ws, size_t ws_size,
                              hipStream_t stream) {
  const float* states   = (const float*)d_in[0];
  const float* policies = (const float*)d_in[1];
  const float* actions  = (const float*)d_in[2];
  const float* W_se_pre = (const float*)d_in[3];
  const float* b_se_pre = (const float*)d_in[4];
  const float* W_key    = (const float*)d_in[5];
  const float* W_query  = (const float*)d_in[6];
  const float* W_se     = (const float*)d_in[7];
  const float* b_se     = (const float*)d_in[8];
  const float* W_sap    = (const float*)d_in[9];
  const float* b_sap    = (const float*)d_in[10];
  const float* W_av     = (const float*)d_in[11];
  const float* W_f1     = (const float*)d_in[12];
  const float* W_f2     = (const float*)d_in[13];
  float* out = (float*)d_out;
  float* ws  = (float*)d_ws;

  transpose_all<<<dim3(64, 7), dim3(256), 0, stream>>>(
      W_se_pre, W_query, W_key, W_se, W_sap, W_av, W_f1, ws);

  if (ws_size >= NEED_BYTES) {
    P1<true><<<dim3(512), dim3(256), 0, stream>>>(
        states, policies, actions, b_sap, b_se_pre, ws,
        ws + OFF_AVACT, ws + OFF_HD);
    P3<<<dim3(512), dim3(256), 0, stream>>>(b_se, ws, out);
    P4<<<dim3(512), dim3(256), 0, stream>>>(W_f2, ws, out);
  } else {
    P1<false><<<dim3(512), dim3(256), 0, stream>>>(
        states, policies, actions, b_sap, b_se_pre, ws,
        ws + OFF_AVACT_F, ws + OFF_HD_F);
    stage12<<<dim3(64), dim3(512), 0, stream>>>(states, b_se_pre, b_se, ws, out);
    finale<<<dim3(64), dim3(512), 0, stream>>>(W_f2, ws, ws + OFF_AVACT_F,
                                               ws + OFF_HD_F, out);
  }
}

// Round 5
// 81.859 us; speedup vs baseline: 7.7852x; 1.5163x over previous
//
#include <hip/hip_runtime.h>

#define DEVFN __device__ __forceinline__

constexpr int BNN = 64 * 64 * 64;              // 262144 per output tensor
constexpr float SCALE = 0.08838834764831845f;  // 1/sqrt(128)
constexpr float NSLOPE = 0.01f;

// ---- ws layout (floats) ----
constexpr int OFF_WPRET = 0;       // [64][128]
constexpr int OFF_WQT   = 8192;    // [128][128]
constexpr int OFF_WKT   = 24576;   // [128][128]
constexpr int OFF_WSET  = 40960;   // [128][128]
constexpr int OFF_WSAPT = 57344;   // [96][128]
constexpr int OFF_WAVT  = 69632;   // [128][128]
constexpr int OFF_WF1T  = 86016;   // [128][64]
constexpr int OFF_E     = 98304;    // [4096][128]
constexpr int OFF_Q     = 622592;   // [4096][128]  q1 then q2 (same-row aliasing, safe)
constexpr int OFF_K1    = 1146880;  // [B][128][64] feature-major
constexpr int OFF_K2    = 1671168;  // [B][128][64] feature-major
constexpr int OFF_AVACT = 2195456;  // [B][64][128]
constexpr int OFF_HD    = 2719744;  // [B][64][64]

// ============ staging: global (tight) -> LDS (padded pitch), 512 threads ============

// [KH][128] tile -> Bs pitch 132 (conflict-free ds_read_b128 in compute)
DEVFN void stage128(int tid, const float* __restrict__ src, float* __restrict__ Bs, int KH) {
  const int n4 = KH * 32;
  for (int idx = tid; idx < n4; idx += 512) {
    const int kk = idx >> 5, c4 = idx & 31;
    *reinterpret_cast<float4*>(&Bs[kk * 132 + c4 * 4]) =
        *reinterpret_cast<const float4*>(&src[kk * 128 + c4 * 4]);
  }
}

// [128][64] tile -> Bs pitch 68
DEVFN void stage64(int tid, const float* __restrict__ src, float* __restrict__ Bs) {
  for (int idx = tid; idx < 2048; idx += 512) {
    const int kk = idx >> 4, c4 = idx & 15;
    *reinterpret_cast<float4*>(&Bs[kk * 68 + c4 * 4]) =
        *reinterpret_cast<const float4*>(&src[kk * 64 + c4 * 4]);
  }
}

// ============ LDS-fed GEMM cores: 16 rows x 128 cols, 512 thr, 1 row x 4 cols ============
// cg = tid&31 (c0 = 4*cg), rg = tid>>5 (row). B reads: 32 distinct float4/wave (2-way
// broadcast) = conflict-free. A reads: wave-broadcast.

DEVFN void g4L(int tid, const float* __restrict__ A, int lda,
               const float* __restrict__ Bs, int KH, float (&acc)[4]) {
  const int cg = tid & 31, rg = tid >> 5, c0 = cg * 4;
#pragma unroll 8
  for (int k = 0; k < KH; ++k) {
    const float4 bv = *reinterpret_cast<const float4*>(&Bs[k * 132 + c0]);
    const float a = A[rg * lda + k];
    acc[0] += a * bv.x; acc[1] += a * bv.y; acc[2] += a * bv.z; acc[3] += a * bv.w;
  }
}

DEVFN void g4L_dualA(int tid, const float* __restrict__ A0, const float* __restrict__ A1,
                     int lda, const float* __restrict__ Bs, int KH,
                     float (&a0)[4], float (&a1)[4]) {
  const int cg = tid & 31, rg = tid >> 5, c0 = cg * 4;
#pragma unroll 8
  for (int k = 0; k < KH; ++k) {
    const float4 bv = *reinterpret_cast<const float4*>(&Bs[k * 132 + c0]);
    const float x = A0[rg * lda + k];
    const float y = A1[rg * lda + k];
    a0[0] += x * bv.x; a0[1] += x * bv.y; a0[2] += x * bv.z; a0[3] += x * bv.w;
    a1[0] += y * bv.x; a1[1] += y * bv.y; a1[2] += y * bv.z; a1[3] += y * bv.w;
  }
}

// 16 rows x 64 cols, 512 thr, 1 row x 2 cols. B pitch 68, float2 reads (even start,
// covers words 0..63 -> 2-way = free).
DEVFN void g2L(int tid, const float* __restrict__ A, int lda,
               const float* __restrict__ Bs, int K, float (&acc)[2]) {
  const int cg = tid & 31, rg = tid >> 5, c0 = cg * 2;
#pragma unroll 8
  for (int k = 0; k < K; ++k) {
    const float2 bv = *reinterpret_cast<const float2*>(&Bs[k * 68 + c0]);
    const float a = A[rg * lda + k];
    acc[0] += a * bv.x; acc[1] += a * bv.y;
  }
}

template<bool ACT, bool HASB>
DEVFN void e4(int tid, float (&acc)[4], float* __restrict__ O, int ldo,
              const float* __restrict__ bias) {
  const int cg = tid & 31, rg = tid >> 5, c0 = cg * 4;
  float t[4];
#pragma unroll
  for (int i = 0; i < 4; ++i) {
    float x = acc[i];
    if constexpr (HASB) x += bias[c0 + i];
    if constexpr (ACT) x = (x > 0.f) ? x : NSLOPE * x;
    t[i] = x;
  }
  float4 v; v.x = t[0]; v.y = t[1]; v.z = t[2]; v.w = t[3];
  *reinterpret_cast<float4*>(&O[rg * ldo + c0]) = v;
}

// feature-major global write: O[(c0+i)*64 + rg]
DEVFN void e4t(int tid, float (&acc)[4], float* __restrict__ O) {
  const int cg = tid & 31, rg = tid >> 5, c0 = cg * 4;
#pragma unroll
  for (int i = 0; i < 4; ++i) O[(c0 + i) * 64 + rg] = acc[i];
}

DEVFN void e2(int tid, float (&acc)[2], float* __restrict__ O, int ldo) {
  const int cg = tid & 31, rg = tid >> 5, c0 = cg * 2;
  float2 v; v.x = acc[0]; v.y = acc[1];
  *reinterpret_cast<float2*>(&O[rg * ldo + c0]) = v;
}

// scores = q @ K^T for 16 rows (K feature-major [128][64], staged in 2 halves),
// softmax in-register. Writes Wp (pitch 68) + gout (row-major, 16x64).
DEVFN void score16(int tid, const float* __restrict__ qrow, const float* __restrict__ kb,
                   float* Ks, float* Wp, float* __restrict__ gout) {
  const int j = tid & 63, iw = tid >> 6;
  float acc2[2] = {0.f, 0.f};
  for (int h = 0; h < 2; ++h) {
    __syncthreads();
    for (int idx = tid; idx < 1024; idx += 512) {
      const int kk = idx >> 4, j4 = idx & 15;
      *reinterpret_cast<float4*>(&Ks[kk * 64 + j4 * 4]) =
          *reinterpret_cast<const float4*>(&kb[(h * 64 + kk) * 64 + j4 * 4]);
    }
    __syncthreads();
#pragma unroll 2
    for (int kt = 0; kt < 64; kt += 8) {
      float qv[2][8];
#pragma unroll
      for (int r = 0; r < 2; ++r) {
        *reinterpret_cast<float4*>(&qv[r][0]) =
            *reinterpret_cast<const float4*>(&qrow[(iw * 2 + r) * 128 + h * 64 + kt]);
        *reinterpret_cast<float4*>(&qv[r][4]) =
            *reinterpret_cast<const float4*>(&qrow[(iw * 2 + r) * 128 + h * 64 + kt + 4]);
      }
#pragma unroll
      for (int kk = 0; kk < 8; ++kk) {
        const float kv = Ks[(kt + kk) * 64 + j];
        acc2[0] += qv[0][kk] * kv;
        acc2[1] += qv[1][kk] * kv;
      }
    }
  }
#pragma unroll
  for (int r = 0; r < 2; ++r) {
    float v = acc2[r] * SCALE;
    float m = v;
#pragma unroll
    for (int off = 32; off > 0; off >>= 1) m = fmaxf(m, __shfl_xor(m, off, 64));
    const float p = __expf(v - m);
    float s = p;
#pragma unroll
    for (int off = 32; off > 0; off >>= 1) s += __shfl_xor(s, off, 64);
    const float w = p / s;
    Wp[(iw * 2 + r) * 68 + j] = w;
    gout[(iw * 2 + r) * 64 + j] = w;
  }
}

// ===================== kernels =====================

__global__ void transpose_all(const float* __restrict__ Wpre, const float* __restrict__ Wq,
                              const float* __restrict__ Wk, const float* __restrict__ Wse,
                              const float* __restrict__ Wsap, const float* __restrict__ Wav,
                              const float* __restrict__ Wf1, float* __restrict__ ws) {
  const int m = blockIdx.y;
  const float* src; int Cout, K, off;
  switch (m) {
    case 0: src = Wpre; Cout = 128; K = 64;  off = OFF_WPRET; break;
    case 1: src = Wq;   Cout = 128; K = 128; off = OFF_WQT;   break;
    case 2: src = Wk;   Cout = 128; K = 128; off = OFF_WKT;   break;
    case 3: src = Wse;  Cout = 128; K = 128; off = OFF_WSET;  break;
    case 4: src = Wsap; Cout = 128; K = 96;  off = OFF_WSAPT; break;
    case 5: src = Wav;  Cout = 128; K = 128; off = OFF_WAVT;  break;
    default: src = Wf1; Cout = 64;  K = 128; off = OFF_WF1T;  break;
  }
  const int idx = blockIdx.x * 256 + threadIdx.x;
  if (idx < Cout * K) {
    const int c = idx / K, k = idx - c * K;
    ws[off + k * Cout + c] = src[idx];
  }
}

// P1: grid 256 (b*4+rq), 512 thr, 16 rows. Full per-row prep:
// E_act/E_pol -> av_act/delta -> hd ; e -> q1/k1.
__global__ __launch_bounds__(512) void P1(const float* __restrict__ states,
                                          const float* __restrict__ policies,
                                          const float* __restrict__ actions,
                                          const float* __restrict__ b_sap,
                                          const float* __restrict__ b_se_pre,
                                          float* __restrict__ ws) {
  __shared__ float Xa[16 * 100];
  __shared__ float Xp[16 * 100];
  __shared__ float Ea[16 * 132];
  __shared__ float Ep[16 * 132];
  __shared__ float Dd[16 * 132];
  __shared__ float Er[16 * 132];
  __shared__ float Bs[8704];  // [64][132] or [128][68]
  const int tid = threadIdx.x;
  const int b = blockIdx.x >> 2, rq = blockIdx.x & 3;
  const int r0g = b * 64 + rq * 16;

  for (int idx = tid; idx < 1024; idx += 512) {
    const int r = idx >> 6, c = idx & 63;
    const float s = states[(r0g + r) * 64 + c];
    Xa[r * 100 + c] = s;
    Xp[r * 100 + c] = s;
  }
  {
    const int r = tid >> 5, c = tid & 31;
    Xa[r * 100 + 64 + c] = actions[(r0g + r) * 32 + c];
    Xp[r * 100 + 64 + c] = policies[(r0g + r) * 32 + c];
  }
  // E_act/E_pol = lrelu(X @ Wsap^T + b_sap), K=96 in halves 64+32
  float aa[4] = {}, ap[4] = {};
  stage128(tid, ws + OFF_WSAPT, Bs, 64);
  __syncthreads();
  g4L_dualA(tid, Xa, Xp, 100, Bs, 64, aa, ap);
  __syncthreads();
  stage128(tid, ws + OFF_WSAPT + 64 * 128, Bs, 32);
  __syncthreads();
  g4L_dualA(tid, Xa + 64, Xp + 64, 100, Bs, 32, aa, ap);
  e4<true, true>(tid, aa, Ea, 132, b_sap);
  e4<true, true>(tid, ap, Ep, 132, b_sap);
  __syncthreads();
  // Ep -= Ea
  for (int idx = tid; idx < 2048; idx += 512) {
    const int r = idx >> 7, c = idx & 127;
    Ep[r * 132 + c] -= Ea[r * 132 + c];
  }
  __syncthreads();
  // av_act (global) & delta (LDS), K=128
  float av[4] = {}, dl[4] = {};
  stage128(tid, ws + OFF_WAVT, Bs, 64);
  __syncthreads();
  g4L_dualA(tid, Ea, Ep, 132, Bs, 64, av, dl);
  __syncthreads();
  stage128(tid, ws + OFF_WAVT + 8192, Bs, 64);
  __syncthreads();
  g4L_dualA(tid, Ea + 64, Ep + 64, 132, Bs, 64, av, dl);
  e4<false, false>(tid, av, ws + OFF_AVACT + r0g * 128, 128, nullptr);
  e4<false, false>(tid, dl, Dd, 132, nullptr);
  __syncthreads();
  // hd = delta @ Wf1^T, K=128, 64 cols
  stage64(tid, ws + OFF_WF1T, Bs);
  __syncthreads();
  {
    float ah[2] = {};
    g2L(tid, Dd, 132, Bs, 128, ah);
    e2(tid, ah, ws + OFF_HD + r0g * 64, 64);
  }
  __syncthreads();
  // e = lrelu(states @ Wpre^T + b_se_pre), K=64 -> Er + ws.E
  stage128(tid, ws + OFF_WPRET, Bs, 64);
  __syncthreads();
  {
    float ae[4] = {};
    g4L(tid, Xa, 100, Bs, 64, ae);
    const int cg = tid & 31, rg = tid >> 5, c0 = cg * 4;
    float t[4];
#pragma unroll
    for (int i = 0; i < 4; ++i) {
      float x = ae[i] + b_se_pre[c0 + i];
      t[i] = (x > 0.f) ? x : NSLOPE * x;
    }
    float4 v; v.x = t[0]; v.y = t[1]; v.z = t[2]; v.w = t[3];
    *reinterpret_cast<float4*>(&Er[rg * 132 + c0]) = v;
    *reinterpret_cast<float4*>(&ws[OFF_E + (r0g + rg) * 128 + c0]) = v;
  }
  __syncthreads();
  // q1 = e @ Wq^T, K=128
  float aq[4] = {};
  stage128(tid, ws + OFF_WQT, Bs, 64);
  __syncthreads();
  g4L(tid, Er, 132, Bs, 64, aq);
  __syncthreads();
  stage128(tid, ws + OFF_WQT + 8192, Bs, 64);
  __syncthreads();
  g4L(tid, Er + 64, 132, Bs, 64, aq);
  e4<false, false>(tid, aq, ws + OFF_Q + r0g * 128, 128, nullptr);
  __syncthreads();
  // k1 = e @ Wk^T, K=128, feature-major out
  float ak[4] = {};
  stage128(tid, ws + OFF_WKT, Bs, 64);
  __syncthreads();
  g4L(tid, Er, 132, Bs, 64, ak);
  __syncthreads();
  stage128(tid, ws + OFF_WKT + 8192, Bs, 64);
  __syncthreads();
  g4L(tid, Er + 64, 132, Bs, 64, ak);
  e4t(tid, ak, ws + OFF_K1 + b * 8192 + rq * 16);
}

// P3: grid 256, 512 thr, 16 rows. score1+softmax -> w_pre; av_pre; se; q2/k2.
__global__ __launch_bounds__(512) void P3(const float* __restrict__ b_se,
                                          float* __restrict__ ws,
                                          float* __restrict__ out) {
  __shared__ float Ks[64 * 64];
  __shared__ float Wp[16 * 68];
  __shared__ float AV[16 * 132];
  __shared__ float SEr[16 * 132];
  __shared__ float Bs[8448];  // [64][132]
  const int tid = threadIdx.x;
  const int b = blockIdx.x >> 2, rq = blockIdx.x & 3;
  const int r0g = b * 64 + rq * 16;

  score16(tid, ws + OFF_Q + r0g * 128, ws + OFF_K1 + b * 8192, Ks, Wp,
          out + BNN + b * 4096 + rq * 1024);
  __syncthreads();
  // av_pre = w_pre @ e[b], K=64
  stage128(tid, ws + OFF_E + b * 8192, Bs, 64);
  __syncthreads();
  {
    float a[4] = {};
    g4L(tid, Wp, 68, Bs, 64, a);
    e4<false, false>(tid, a, AV, 132, nullptr);
  }
  __syncthreads();
  // se = lrelu(av_pre @ Wse^T + b_se), K=128
  float as[4] = {};
  stage128(tid, ws + OFF_WSET, Bs, 64);
  __syncthreads();
  g4L(tid, AV, 132, Bs, 64, as);
  __syncthreads();
  stage128(tid, ws + OFF_WSET + 8192, Bs, 64);
  __syncthreads();
  g4L(tid, AV + 64, 132, Bs, 64, as);
  e4<true, true>(tid, as, SEr, 132, b_se);
  __syncthreads();
  // q2
  float aq[4] = {};
  stage128(tid, ws + OFF_WQT, Bs, 64);
  __syncthreads();
  g4L(tid, SEr, 132, Bs, 64, aq);
  __syncthreads();
  stage128(tid, ws + OFF_WQT + 8192, Bs, 64);
  __syncthreads();
  g4L(tid, SEr + 64, 132, Bs, 64, aq);
  e4<false, false>(tid, aq, ws + OFF_Q + r0g * 128, 128, nullptr);
  __syncthreads();
  // k2
  float ak[4] = {};
  stage128(tid, ws + OFF_WKT, Bs, 64);
  __syncthreads();
  g4L(tid, SEr, 132, Bs, 64, ak);
  __syncthreads();
  stage128(tid, ws + OFF_WKT + 8192, Bs, 64);
  __syncthreads();
  g4L(tid, SEr + 64, 132, Bs, 64, ak);
  e4t(tid, ak, ws + OFF_K2 + b * 8192 + rq * 16);
}

// P4: grid 256, 512 thr, 16 rows. score2 -> w; node; h_base; head -> value.
__global__ __launch_bounds__(512) void P4(const float* __restrict__ Wf2g,
                                          float* __restrict__ ws,
                                          float* __restrict__ out) {
  __shared__ float Ks[64 * 64];
  __shared__ float Wp[16 * 68];
  __shared__ float NB[16 * 132];
  __shared__ float Hb[16 * 68];
  __shared__ float Hd[64 * 69];
  __shared__ float Wf2s[64];
  __shared__ float Bs[8704];
  const int tid = threadIdx.x;
  const int b = blockIdx.x >> 2, rq = blockIdx.x & 3;
  const int r0g = b * 64 + rq * 16;

  for (int idx = tid; idx < 4096; idx += 512)
    Hd[(idx >> 6) * 69 + (idx & 63)] = ws[OFF_HD + b * 4096 + idx];
  if (tid < 64) Wf2s[tid] = Wf2g[tid];

  score16(tid, ws + OFF_Q + r0g * 128, ws + OFF_K2 + b * 8192, Ks, Wp,
          out + 2 * BNN + b * 4096 + rq * 1024);
  __syncthreads();
  // node = w @ av_act[b], K=64
  stage128(tid, ws + OFF_AVACT + b * 8192, Bs, 64);
  __syncthreads();
  {
    float a[4] = {};
    g4L(tid, Wp, 68, Bs, 64, a);
    e4<false, false>(tid, a, NB, 132, nullptr);
  }
  __syncthreads();
  // h_base = node @ Wf1^T (no activation), K=128, 64 cols
  stage64(tid, ws + OFF_WF1T, Bs);
  __syncthreads();
  {
    float ah[2] = {};
    g2L(tid, NB, 132, Bs, 128, ah);
    e2(tid, ah, Hb, 68);
  }
  __syncthreads();
  // head: value[i][j] = sum_f lrelu(hb[i,f] + w[i,j]*hd[j,f]) * Wf2[f]
  const int j = tid & 63, iw = tid >> 6;
  float wv[2], a2[2] = {0.f, 0.f};
#pragma unroll
  for (int r = 0; r < 2; ++r) wv[r] = Wp[(iw * 2 + r) * 68 + j];
  for (int f = 0; f < 64; ++f) {
    const float hdv = Hd[j * 69 + f];
    const float wf = Wf2s[f];
#pragma unroll
    for (int r = 0; r < 2; ++r) {
      float t = Hb[(iw * 2 + r) * 68 + f] + wv[r] * hdv;
      t = (t > 0.f) ? t : NSLOPE * t;
      a2[r] += t * wf;
    }
  }
#pragma unroll
  for (int r = 0; r < 2; ++r)
    out[(r0g + iw * 2 + r) * 64 + j] = a2[r];
}

extern "C" void kernel_launch(void* const* d_in, const int* in_sizes, int n_in,
                              void* d_out, int out_size, void* d_ws, size_t ws_size,
                              hipStream_t stream) {
  const float* states   = (const float*)d_in[0];
  const float* policies = (const float*)d_in[1];
  const float* actions  = (const float*)d_in[2];
  const float* W_se_pre = (const float*)d_in[3];
  const float* b_se_pre = (const float*)d_in[4];
  const float* W_key    = (const float*)d_in[5];
  const float* W_query  = (const float*)d_in[6];
  const float* W_se     = (const float*)d_in[7];
  const float* b_se     = (const float*)d_in[8];
  const float* W_sap    = (const float*)d_in[9];
  const float* b_sap    = (const float*)d_in[10];
  const float* W_av     = (const float*)d_in[11];
  const float* W_f1     = (const float*)d_in[12];
  const float* W_f2     = (const float*)d_in[13];
  float* out = (float*)d_out;
  float* ws  = (float*)d_ws;

  transpose_all<<<dim3(64, 7), dim3(256), 0, stream>>>(
      W_se_pre, W_query, W_key, W_se, W_sap, W_av, W_f1, ws);
  P1<<<dim3(256), dim3(512), 0, stream>>>(states, policies, actions, b_sap, b_se_pre, ws);
  P3<<<dim3(256), dim3(512), 0, stream>>>(b_se, ws, out);
  P4<<<dim3(256), dim3(512), 0, stream>>>(W_f2, ws, out);
}